// Round 1
// baseline (2258.051 us; speedup 1.0000x reference)
//
#include <hip/hip_runtime.h>
#include <cstdint>
#include <cstddef>
#include <math.h>

// Problem constants
constexpr int Bc   = 2;
constexpr int Sc   = 2048;
constexpr int Hc   = 2048;
constexpr int NQc  = 16;
constexpr int NKVc = 4;
constexpr int Dc   = 128;
#define SCALE_F 0.08838834764831845f   // 1/sqrt(128)

// ---------------------------------------------------------------------------
// GEMM 1: qkv = x @ [Wq;Wk;Wv]^T + bias, epilogue scatters to Q/newK/newV
// C[m][n], m in [0,4096) = (b,s), n in [0,3072). 128x128 tile, BK=8, 256 thr,
// 8x8 microtile per thread (cols split as tx*4 and 64+tx*4 for bank-freedom).
// ---------------------------------------------------------------------------
__global__ __launch_bounds__(256) void gemm_qkv_kernel(
    const float* __restrict__ x,
    const float* __restrict__ Wq, const float* __restrict__ bq,
    const float* __restrict__ Wk, const float* __restrict__ bk,
    const float* __restrict__ Wv, const float* __restrict__ bv,
    float* __restrict__ qbuf, float* __restrict__ kbuf, float* __restrict__ vbuf)
{
    __shared__ __align__(16) float As[8][132];
    __shared__ __align__(16) float Bs[8][132];

    const int tid = threadIdx.x;
    const int m0 = blockIdx.x * 128;
    const int n0 = blockIdx.y * 128;   // [0,3072), 128-tile always inside one W

    const float* W; const float* bias;
    if (n0 < 2048)      { W = Wq + (size_t)n0 * 2048;          bias = bq + n0; }
    else if (n0 < 2560) { W = Wk + (size_t)(n0 - 2048) * 2048; bias = bk + (n0 - 2048); }
    else                { W = Wv + (size_t)(n0 - 2560) * 2048; bias = bv + (n0 - 2560); }

    const int lrow = tid >> 1;          // 0..127
    const int lk   = (tid & 1) << 2;    // 0 or 4
    const float* Ap = x + (size_t)(m0 + lrow) * 2048 + lk;
    const float* Bp = W + (size_t)lrow * 2048 + lk;

    const int ty = tid >> 4;            // 0..15 -> rows ty*8..+7
    const int tx = tid & 15;            // 0..15 -> cols tx*4..+3 and 64+tx*4..+3

    float acc[8][8];
    #pragma unroll
    for (int i = 0; i < 8; ++i)
        #pragma unroll
        for (int j = 0; j < 8; ++j) acc[i][j] = 0.f;

    float4 a = *(const float4*)(Ap);
    float4 b = *(const float4*)(Bp);

    for (int k0 = 0; k0 < 2048; k0 += 8) {
        __syncthreads();
        As[lk+0][lrow] = a.x; As[lk+1][lrow] = a.y; As[lk+2][lrow] = a.z; As[lk+3][lrow] = a.w;
        Bs[lk+0][lrow] = b.x; Bs[lk+1][lrow] = b.y; Bs[lk+2][lrow] = b.z; Bs[lk+3][lrow] = b.w;
        __syncthreads();
        if (k0 + 8 < 2048) {           // prefetch next k-slab during compute
            a = *(const float4*)(Ap + k0 + 8);
            b = *(const float4*)(Bp + k0 + 8);
        }
        #pragma unroll
        for (int kk = 0; kk < 8; ++kk) {
            float af[8], bf[8];
            *(float4*)&af[0] = *(const float4*)&As[kk][ty*8];
            *(float4*)&af[4] = *(const float4*)&As[kk][ty*8 + 4];
            *(float4*)&bf[0] = *(const float4*)&Bs[kk][tx*4];
            *(float4*)&bf[4] = *(const float4*)&Bs[kk][64 + tx*4];
            #pragma unroll
            for (int i = 0; i < 8; ++i)
                #pragma unroll
                for (int j = 0; j < 8; ++j)
                    acc[i][j] = fmaf(af[i], bf[j], acc[i][j]);
        }
    }

    // Epilogue: scatter with bias. Block's 128 cols are entirely in one region.
    #pragma unroll
    for (int i = 0; i < 8; ++i) {
        const int m = m0 + ty*8 + i;
        const int bb = m >> 11;         // batch
        const int ss = m & 2047;        // seq
        #pragma unroll
        for (int q = 0; q < 2; ++q) {
            const int cm = q*64 + tx*4;       // col within tile
            float4 v;
            v.x = acc[i][q*4+0] + bias[cm+0];
            v.y = acc[i][q*4+1] + bias[cm+1];
            v.z = acc[i][q*4+2] + bias[cm+2];
            v.w = acc[i][q*4+3] + bias[cm+3];
            const int n = n0 + cm;            // global col
            float* dst;
            if (n < 2048) {
                const int head = n >> 7, d = n & 127;
                dst = qbuf + (((size_t)(bb*NQc + head) * Sc) + ss) * Dc + d;
            } else if (n < 2560) {
                const int nk = n - 2048; const int head = nk >> 7, d = nk & 127;
                dst = kbuf + (((size_t)(bb*NKVc + head) * Sc) + ss) * Dc + d;
            } else {
                const int nv = n - 2560; const int head = nv >> 7, d = nv & 127;
                dst = vbuf + (((size_t)(bb*NKVc + head) * Sc) + ss) * Dc + d;
            }
            *(float4*)dst = v;
        }
    }
}

// ---------------------------------------------------------------------------
// GEMM 2: out = attn_out @ Wo^T.  Same structure, plain row-major write.
// ---------------------------------------------------------------------------
__global__ __launch_bounds__(256) void gemm_out_kernel(
    const float* __restrict__ A,      // [4096, 2048]
    const float* __restrict__ Wo,     // [2048, 2048]
    float* __restrict__ C)            // [4096, 2048]
{
    __shared__ __align__(16) float As[8][132];
    __shared__ __align__(16) float Bs[8][132];

    const int tid = threadIdx.x;
    const int m0 = blockIdx.x * 128;
    const int n0 = blockIdx.y * 128;

    const int lrow = tid >> 1;
    const int lk   = (tid & 1) << 2;
    const float* Ap = A  + (size_t)(m0 + lrow) * 2048 + lk;
    const float* Bp = Wo + (size_t)(n0 + lrow) * 2048 + lk;

    const int ty = tid >> 4;
    const int tx = tid & 15;

    float acc[8][8];
    #pragma unroll
    for (int i = 0; i < 8; ++i)
        #pragma unroll
        for (int j = 0; j < 8; ++j) acc[i][j] = 0.f;

    float4 a = *(const float4*)(Ap);
    float4 b = *(const float4*)(Bp);

    for (int k0 = 0; k0 < 2048; k0 += 8) {
        __syncthreads();
        As[lk+0][lrow] = a.x; As[lk+1][lrow] = a.y; As[lk+2][lrow] = a.z; As[lk+3][lrow] = a.w;
        Bs[lk+0][lrow] = b.x; Bs[lk+1][lrow] = b.y; Bs[lk+2][lrow] = b.z; Bs[lk+3][lrow] = b.w;
        __syncthreads();
        if (k0 + 8 < 2048) {
            a = *(const float4*)(Ap + k0 + 8);
            b = *(const float4*)(Bp + k0 + 8);
        }
        #pragma unroll
        for (int kk = 0; kk < 8; ++kk) {
            float af[8], bf[8];
            *(float4*)&af[0] = *(const float4*)&As[kk][ty*8];
            *(float4*)&af[4] = *(const float4*)&As[kk][ty*8 + 4];
            *(float4*)&bf[0] = *(const float4*)&Bs[kk][tx*4];
            *(float4*)&bf[4] = *(const float4*)&Bs[kk][64 + tx*4];
            #pragma unroll
            for (int i = 0; i < 8; ++i)
                #pragma unroll
                for (int j = 0; j < 8; ++j)
                    acc[i][j] = fmaf(af[i], bf[j], acc[i][j]);
        }
    }

    #pragma unroll
    for (int i = 0; i < 8; ++i) {
        const int m = m0 + ty*8 + i;
        #pragma unroll
        for (int q = 0; q < 2; ++q) {
            const int cm = q*64 + tx*4;
            float4 v;
            v.x = acc[i][q*4+0]; v.y = acc[i][q*4+1];
            v.z = acc[i][q*4+2]; v.w = acc[i][q*4+3];
            *(float4*)(C + (size_t)m * 2048 + n0 + cm) = v;
        }
    }
}

// ---------------------------------------------------------------------------
// RoPE in-place on Q [B,NQ,S,D] and newK [B,NKV,S,D].
// One thread per (b, head<20, s, dpair<64).
// ---------------------------------------------------------------------------
__global__ __launch_bounds__(256) void rope_kernel(
    float* __restrict__ qbuf, float* __restrict__ kbuf,
    const float* __restrict__ cosb, const float* __restrict__ sinb)
{
    const int idx = blockIdx.x * 256 + threadIdx.x;   // < 2*20*2048*64
    const int dp = idx & 63;
    int t = idx >> 6;
    const int ss = t & 2047;
    t >>= 11;                 // = b*20 + h
    const int h  = t % 20;
    const int bb = t / 20;

    float* base;
    if (h < NQc) base = qbuf + (((size_t)(bb*NQc + h) * Sc) + ss) * Dc;
    else         base = kbuf + (((size_t)(bb*NKVc + (h - NQc)) * Sc) + ss) * Dc;

    const float* cp = cosb + ((size_t)bb * Sc + ss) * Dc;
    const float* sp = sinb + ((size_t)bb * Sc + ss) * Dc;

    const float x1 = base[dp], x2 = base[dp + 64];
    const float c1 = cp[dp],   c2 = cp[dp + 64];
    const float s1 = sp[dp],   s2 = sp[dp + 64];
    base[dp]      = x1 * c1 - x2 * s1;   // rot_half first half = -x2
    base[dp + 64] = x2 * c2 + x1 * s2;   // rot_half second half = +x1
}

// ---------------------------------------------------------------------------
// Causal GQA flash attention, fp32.
// Block: 256 thr, TQ=64 q-rows for one (b,h). K-chunks of TK=32.
// LDS: Qs d-major [128][68] (34.0KB), U union {K d-major [128][34] | V [32][128]}
// (17.0KB), Ps [32][68] (8.5KB) -> 59.5KB static, 2 blocks/CU.
// thread (ty=tid/16, tx=tid%16): scores rows ty*4..+3 x keys tx*2..+1;
// output rows ty*4..+3 x dims {tx*4..+3, 64+tx*4..+3}.
// ---------------------------------------------------------------------------
__global__ __launch_bounds__(256) void attn_kernel(
    const float* __restrict__ Q, const float* __restrict__ K,
    const float* __restrict__ V, float* __restrict__ Aout)
{
    __shared__ __align__(16) float Qs[128][68];
    __shared__ __align__(16) float U[128 * 34];     // K: [d][34]+key ; V: [k*128]+d
    __shared__ __align__(16) float Ps[32][68];

    const int tid = threadIdx.x;
    const int qt = 31 - blockIdx.x;        // heavy tiles dispatched first
    const int bh = blockIdx.y;             // b*16 + h
    const int bb = bh >> 4, h = bh & 15, hk = h >> 2;

    const float* Qp = Q + (((size_t)(bb*NQc + h) * Sc) + (size_t)qt*64) * Dc;
    const float* Kp = K + ((size_t)(bb*NKVc + hk) * Sc) * Dc;
    const float* Vp = V + ((size_t)(bb*NKVc + hk) * Sc) * Dc;

    const int ty = tid >> 4, tx = tid & 15;

    // Stage Q tile (64 x 128) transposed -> Qs[d][row]
    #pragma unroll
    for (int i = 0; i < 8; ++i) {
        const int flat = tid + 256*i;       // float4 index
        const int r  = flat >> 5;
        const int d4 = (flat & 31) << 2;
        const float4 qv = *(const float4*)(Qp + (size_t)r * Dc + d4);
        Qs[d4+0][r] = qv.x; Qs[d4+1][r] = qv.y; Qs[d4+2][r] = qv.z; Qs[d4+3][r] = qv.w;
    }

    float m_r[4], l_r[4], o[4][8];
    #pragma unroll
    for (int i = 0; i < 4; ++i) {
        m_r[i] = -__builtin_inff(); l_r[i] = 0.f;
        #pragma unroll
        for (int j = 0; j < 8; ++j) o[i][j] = 0.f;
    }

    const int kend = qt*64 + 64;
    for (int kb = 0; kb < kend; kb += 32) {
        __syncthreads();   // previous chunk's PV reads of U(V)/Ps complete

        // Stage K (transposed) into U; prefetch V into registers.
        float4 vreg[4];
        #pragma unroll
        for (int i = 0; i < 4; ++i) {
            const int flat = tid + 256*i;
            const int r  = flat >> 5;
            const int d4 = (flat & 31) << 2;
            const float4 kv = *(const float4*)(Kp + (size_t)(kb + r) * Dc + d4);
            vreg[i]        = *(const float4*)(Vp + (size_t)(kb + r) * Dc + d4);
            U[(d4+0)*34 + r] = kv.x; U[(d4+1)*34 + r] = kv.y;
            U[(d4+2)*34 + r] = kv.z; U[(d4+3)*34 + r] = kv.w;
        }
        __syncthreads();   // K ready

        // QK^T for this chunk
        float sc[4][2] = {{0.f,0.f},{0.f,0.f},{0.f,0.f},{0.f,0.f}};
        #pragma unroll 8
        for (int d = 0; d < 128; ++d) {
            const float4 qv = *(const float4*)&Qs[d][ty*4];
            const float2 kv = *(const float2*)&U[d*34 + tx*2];
            const float qa[4] = {qv.x, qv.y, qv.z, qv.w};
            const float ka[2] = {kv.x, kv.y};
            #pragma unroll
            for (int i = 0; i < 4; ++i)
                #pragma unroll
                for (int j = 0; j < 2; ++j)
                    sc[i][j] = fmaf(qa[i], ka[j], sc[i][j]);
        }

        // scale + causal mask + online softmax
        const int qg0 = qt*64 + ty*4;
        const int kg0 = kb + tx*2;
        float mnew[4], alpha[4];
        #pragma unroll
        for (int i = 0; i < 4; ++i) {
            #pragma unroll
            for (int j = 0; j < 2; ++j) {
                sc[i][j] *= SCALE_F;
                if (kg0 + j > qg0 + i) sc[i][j] = -__builtin_inff();
            }
            float rm = fmaxf(sc[i][0], sc[i][1]);
            rm = fmaxf(rm, __shfl_xor(rm, 1, 16));
            rm = fmaxf(rm, __shfl_xor(rm, 2, 16));
            rm = fmaxf(rm, __shfl_xor(rm, 4, 16));
            rm = fmaxf(rm, __shfl_xor(rm, 8, 16));
            mnew[i]  = fmaxf(m_r[i], rm);
            alpha[i] = __expf(m_r[i] - mnew[i]);   // -inf -> 0 on first chunk
            m_r[i]   = mnew[i];
        }
        // P = exp(S - m), store transposed Ps[key][row]
        #pragma unroll
        for (int j = 0; j < 2; ++j) {
            float4 pv;
            pv.x = __expf(sc[0][j] - mnew[0]);
            pv.y = __expf(sc[1][j] - mnew[1]);
            pv.z = __expf(sc[2][j] - mnew[2]);
            pv.w = __expf(sc[3][j] - mnew[3]);
            *(float4*)&Ps[tx*2 + j][ty*4] = pv;
            sc[0][j] = pv.x; sc[1][j] = pv.y; sc[2][j] = pv.z; sc[3][j] = pv.w;
        }
        #pragma unroll
        for (int i = 0; i < 4; ++i) {
            float rs = sc[i][0] + sc[i][1];
            rs += __shfl_xor(rs, 1, 16);
            rs += __shfl_xor(rs, 2, 16);
            rs += __shfl_xor(rs, 4, 16);
            rs += __shfl_xor(rs, 8, 16);
            l_r[i] = l_r[i] * alpha[i] + rs;
            #pragma unroll
            for (int j = 0; j < 8; ++j) o[i][j] *= alpha[i];
        }
        __syncthreads();   // all QK reads of U(K) done; P fully written

        // Write prefetched V into U (row-major [32][128])
        #pragma unroll
        for (int i = 0; i < 4; ++i) {
            const int flat = tid + 256*i;
            const int r  = flat >> 5;
            const int d4 = (flat & 31) << 2;
            *(float4*)&U[r*128 + d4] = vreg[i];
        }
        __syncthreads();   // V ready

        // PV accumulate
        #pragma unroll 4
        for (int k = 0; k < 32; ++k) {
            const float4 pk = *(const float4*)&Ps[k][ty*4];
            const float4 v0 = *(const float4*)&U[k*128 + tx*4];
            const float4 v1 = *(const float4*)&U[k*128 + 64 + tx*4];
            const float pk4[4] = {pk.x, pk.y, pk.z, pk.w};
            const float vv[8]  = {v0.x, v0.y, v0.z, v0.w, v1.x, v1.y, v1.z, v1.w};
            #pragma unroll
            for (int i = 0; i < 4; ++i)
                #pragma unroll
                for (int j = 0; j < 8; ++j)
                    o[i][j] = fmaf(pk4[i], vv[j], o[i][j]);
        }
    }

    // Epilogue: attn_out[b][s][h][d], normalized
    #pragma unroll
    for (int i = 0; i < 4; ++i) {
        const float inv = 1.f / (l_r[i] + 1e-9f);
        const int srow = qt*64 + ty*4 + i;
        float* dst = Aout + (((size_t)(bb * Sc + srow) * NQc) + h) * Dc;
        float4 v0, v1;
        v0.x = o[i][0]*inv; v0.y = o[i][1]*inv; v0.z = o[i][2]*inv; v0.w = o[i][3]*inv;
        v1.x = o[i][4]*inv; v1.y = o[i][5]*inv; v1.z = o[i][6]*inv; v1.w = o[i][7]*inv;
        *(float4*)(dst + tx*4)      = v0;
        *(float4*)(dst + 64 + tx*4) = v1;
    }
}

// ---------------------------------------------------------------------------
extern "C" void kernel_launch(void* const* d_in, const int* in_sizes, int n_in,
                              void* d_out, int out_size, void* d_ws, size_t ws_size,
                              hipStream_t stream)
{
    const float* x    = (const float*)d_in[0];
    const float* cosb = (const float*)d_in[1];
    const float* sinb = (const float*)d_in[2];
    const float* Wq   = (const float*)d_in[3];
    const float* bq   = (const float*)d_in[4];
    const float* Wk   = (const float*)d_in[5];
    const float* bk   = (const float*)d_in[6];
    const float* Wv   = (const float*)d_in[7];
    const float* bv   = (const float*)d_in[8];
    const float* Wo   = (const float*)d_in[9];

    float* out  = (float*)d_out;                              // [B,S,H]
    float* kout = out  + (size_t)Bc * Sc * Hc;                // new_k [B,NKV,S,D]
    float* vout = kout + (size_t)Bc * NKVc * Sc * Dc;         // new_v [B,NKV,S,D]
    // Q [B,NQ,S,D] is exactly B*S*H floats: reuse the `out` region until the
    // final projection overwrites it (gemm_out reads only ws + Wo).
    float* qbuf = out;
    float* attn = (float*)d_ws;                               // [B,S,NQ,D] = 33.55 MB

    dim3 g1(32, 24);
    gemm_qkv_kernel<<<g1, 256, 0, stream>>>(x, Wq, bq, Wk, bk, Wv, bv, qbuf, kout, vout);

    rope_kernel<<<20480, 256, 0, stream>>>(qbuf, kout, cosb, sinb);

    dim3 g3(32, 32);
    attn_kernel<<<g3, 256, 0, stream>>>(qbuf, kout, vout, attn);

    dim3 g4(32, 16);
    gemm_out_kernel<<<g4, 256, 0, stream>>>(attn, Wo, out);
}

// Round 3
// 381.378 us; speedup vs baseline: 5.9208x; 5.9208x over previous
//
#include <hip/hip_runtime.h>
#include <cstdint>
#include <cstddef>
#include <math.h>

// Problem constants
constexpr int Bc   = 2;
constexpr int Sc   = 2048;
constexpr int Hc   = 2048;
constexpr int NQc  = 16;
constexpr int NKVc = 4;
constexpr int Dc   = 128;
#define SCALE_F 0.08838834764831845f   // 1/sqrt(128)

typedef __attribute__((ext_vector_type(8))) short  bf16x8;
typedef __attribute__((ext_vector_type(4))) float  f32x4;
typedef __attribute__((ext_vector_type(16))) float f32x16;

// ---- helpers ---------------------------------------------------------------
__device__ __forceinline__ uint16_t f2bf(float f) {
    union { float f; uint32_t u; } v; v.f = f;
    uint32_t u = v.u;
    return (uint16_t)((u + 0x7FFFu + ((u >> 16) & 1u)) >> 16);   // RNE
}
__device__ __forceinline__ uint32_t pk2bf(float lo, float hi) {
    return (uint32_t)f2bf(lo) | ((uint32_t)f2bf(hi) << 16);
}
__device__ __forceinline__ float bfu2f(uint16_t u) {
    union { uint32_t u; float f; } v; v.u = (uint32_t)u << 16; return v.f;
}
// async global->LDS, 16B per lane; lds base must be wave-uniform (HW adds lane*16)
__device__ __forceinline__ void lds_load16(void* lds, const void* g) {
    __builtin_amdgcn_global_load_lds(
        (const __attribute__((address_space(1))) uint32_t*)g,
        (__attribute__((address_space(3))) uint32_t*)lds, 16, 0, 0);
}
__device__ __forceinline__ bf16x8 mk8(uint32_t w0, uint32_t w1, uint32_t w2, uint32_t w3) {
    union { uint32_t u[4]; bf16x8 s; } t;
    t.u[0] = w0; t.u[1] = w1; t.u[2] = w2; t.u[3] = w3; return t.s;
}

// ---------------------------------------------------------------------------
// cvt1: f32 -> bf16 for x -> xb and [Wq;Wk;Wv] -> wqkv[3072][2048]
// ---------------------------------------------------------------------------
__global__ __launch_bounds__(256) void cvt1_kernel(
    const float* __restrict__ x,  const float* __restrict__ wq,
    const float* __restrict__ wk, const float* __restrict__ wv,
    uint16_t* __restrict__ xb, uint16_t* __restrict__ wqkv)
{
    const long long TOT = 3670016LL;  // total float4 count
    for (long long i = (long long)blockIdx.x * 256 + threadIdx.x; i < TOT;
         i += (long long)gridDim.x * 256) {
        const float* src; uint16_t* dst; long long off;
        if (i < 2097152LL)      { src = x;  dst = xb;             off = i; }
        else if (i < 3145728LL) { src = wq; dst = wqkv;           off = i - 2097152LL; }
        else if (i < 3407872LL) { src = wk; dst = wqkv + 4194304; off = i - 3145728LL; }
        else                    { src = wv; dst = wqkv + 5242880; off = i - 3407872LL; }
        float4 v = *((const float4*)src + off);
        uint2 o; o.x = pk2bf(v.x, v.y); o.y = pk2bf(v.z, v.w);
        *((uint2*)dst + off) = o;
    }
}

// cvt2: Wo -> bf16 (runs after wqkv region is dead)
__global__ __launch_bounds__(256) void cvt2_kernel(
    const float* __restrict__ wo, uint16_t* __restrict__ wob)
{
    for (long long i = (long long)blockIdx.x * 256 + threadIdx.x; i < 1048576LL;
         i += (long long)gridDim.x * 256) {
        float4 v = *((const float4*)wo + i);
        uint2 o; o.x = pk2bf(v.x, v.y); o.y = pk2bf(v.z, v.w);
        *((uint2*)wob + i) = o;
    }
}

// ---------------------------------------------------------------------------
// Shared GEMM pieces: 128x128 tile, BK=64, 4 waves (2x2 of 64x64), 16x16x32 MFMA.
// LDS tiles [128 rows][64 bf16] with XOR swizzle: 16B-slot ^= (row&7); staged via
// global_load_lds with inverse-swizzled per-lane SOURCE (rule 21), LDS linear.
// ---------------------------------------------------------------------------
__device__ __forceinline__ void gemm_stage(const uint16_t* __restrict__ src,
                                           size_t row_stride, uint16_t* lds,
                                           int wid, int lane)
{
    #pragma unroll
    for (int i = 0; i < 4; ++i) {
        const int g = wid * 4 + i;               // 16 insts per tile, 4/wave
        const int r = g * 8 + (lane >> 3);       // 8 rows per inst (128B rows)
        const int slot = (lane & 7) ^ (r & 7);   // inverse-swizzled source slot
        lds_load16(lds + g * 512, src + (size_t)r * row_stride + slot * 8);
    }
}

#define GEMM_CORE(AS, BS, AB, BB)                                              \
    f32x4 acc[4][4] = {};                                                      \
    gemm_stage(AB, 2048, &AS[0][0], wid, lane);                                \
    gemm_stage(BB, 2048, &BS[0][0], wid, lane);                                \
    __syncthreads();                                                           \
    for (int t = 0; t < 32; ++t) {                                             \
        const int cur = t & 1;                                                 \
        if (t + 1 < 32) {                                                      \
            gemm_stage(AB + (t + 1) * 64, 2048, &AS[cur ^ 1][0], wid, lane);   \
            gemm_stage(BB + (t + 1) * 64, 2048, &BS[cur ^ 1][0], wid, lane);   \
        }                                                                      \
        _Pragma("unroll")                                                      \
        for (int kk = 0; kk < 2; ++kk) {                                       \
            bf16x8 av[4], bw[4];                                               \
            _Pragma("unroll")                                                  \
            for (int mi = 0; mi < 4; ++mi) {                                   \
                const int row = wr * 64 + mi * 16 + (lane & 15);               \
                const int slot = (kk * 4 + (lane >> 4)) ^ (row & 7);           \
                av[mi] = *(const bf16x8*)&AS[cur][row * 64 + slot * 8];        \
            }                                                                  \
            _Pragma("unroll")                                                  \
            for (int nj = 0; nj < 4; ++nj) {                                   \
                const int row = wc * 64 + nj * 16 + (lane & 15);               \
                const int slot = (kk * 4 + (lane >> 4)) ^ (row & 7);           \
                bw[nj] = *(const bf16x8*)&BS[cur][row * 64 + slot * 8];        \
            }                                                                  \
            _Pragma("unroll")                                                  \
            for (int mi = 0; mi < 4; ++mi)                                     \
                _Pragma("unroll")                                              \
                for (int nj = 0; nj < 4; ++nj)                                 \
                    acc[mi][nj] = __builtin_amdgcn_mfma_f32_16x16x32_bf16(     \
                        av[mi], bw[nj], acc[mi][nj], 0, 0, 0);                 \
        }                                                                      \
        __syncthreads();                                                       \
    }

// GEMM1: [4096,2048]bf16 @ wqkv[3072,2048]^T + bias
//   q cols -> bf16 qb2 [b][h][s][d]  (pre-rope; rope applied in-place later)
//   k cols -> fp32 kbuf (new_k, pre-rope; rope in-place later)
//   v cols -> fp32 vbuf (new_v, final)
__global__ __launch_bounds__(256) void gemm_qkv_kernel(
    const uint16_t* __restrict__ xb, const uint16_t* __restrict__ wqkv,
    const float* __restrict__ bq, const float* __restrict__ bk, const float* __restrict__ bv,
    uint16_t* __restrict__ qb2, float* __restrict__ kbuf, float* __restrict__ vbuf)
{
    __shared__ __align__(16) uint16_t As[2][128 * 64];
    __shared__ __align__(16) uint16_t Bs[2][128 * 64];
    const int tid = threadIdx.x, lane = tid & 63, wid = tid >> 6;
    const int m0 = blockIdx.x * 128, n0 = blockIdx.y * 128;
    const int wr = wid >> 1, wc = wid & 1;
    const uint16_t* Ab = xb + (size_t)m0 * 2048;
    const uint16_t* Bb = wqkv + (size_t)n0 * 2048;

    GEMM_CORE(As, Bs, Ab, Bb)

    const float* bias; int rtype; int nbase;
    if (n0 < 2048)      { bias = bq + n0;          rtype = 0; nbase = n0; }
    else if (n0 < 2560) { bias = bk + (n0 - 2048); rtype = 1; nbase = n0 - 2048; }
    else                { bias = bv + (n0 - 2560); rtype = 2; nbase = n0 - 2560; }
    #pragma unroll
    for (int mi = 0; mi < 4; ++mi) {
        #pragma unroll
        for (int nj = 0; nj < 4; ++nj) {
            const int ct = wc * 64 + nj * 16 + (lane & 15);  // tile-local col
            const int nloc = nbase + ct;
            const int head = nloc >> 7, d = nloc & 127;
            const float bval = bias[ct];
            #pragma unroll
            for (int j = 0; j < 4; ++j) {
                const int m = m0 + wr * 64 + mi * 16 + (lane >> 4) * 4 + j;
                const int bb2 = m >> 11, ss = m & 2047;
                const float v = acc[mi][nj][j] + bval;
                if (rtype == 0)
                    qb2[(((size_t)(bb2 * NQc + head) * Sc) + ss) * Dc + d] = f2bf(v);
                else if (rtype == 1)
                    kbuf[(((size_t)(bb2 * NKVc + head) * Sc) + ss) * Dc + d] = v;
                else
                    vbuf[(((size_t)(bb2 * NKVc + head) * Sc) + ss) * Dc + d] = v;
            }
        }
    }
}

// GEMM2: attn_out[4096,2048]bf16 @ Wo[2048,2048]^T -> out fp32
__global__ __launch_bounds__(256) void gemm_out_kernel(
    const uint16_t* __restrict__ ab, const uint16_t* __restrict__ wob,
    float* __restrict__ C)
{
    __shared__ __align__(16) uint16_t As[2][128 * 64];
    __shared__ __align__(16) uint16_t Bs[2][128 * 64];
    const int tid = threadIdx.x, lane = tid & 63, wid = tid >> 6;
    const int m0 = blockIdx.x * 128, n0 = blockIdx.y * 128;
    const int wr = wid >> 1, wc = wid & 1;
    const uint16_t* Ab = ab + (size_t)m0 * 2048;
    const uint16_t* Bb = wob + (size_t)n0 * 2048;

    GEMM_CORE(As, Bs, Ab, Bb)

    #pragma unroll
    for (int mi = 0; mi < 4; ++mi) {
        #pragma unroll
        for (int nj = 0; nj < 4; ++nj) {
            const int n = n0 + wc * 64 + nj * 16 + (lane & 15);
            #pragma unroll
            for (int j = 0; j < 4; ++j) {
                const int m = m0 + wr * 64 + mi * 16 + (lane >> 4) * 4 + j;
                C[(size_t)m * 2048 + n] = acc[mi][nj][j];
            }
        }
    }
}

// ---------------------------------------------------------------------------
// RoPE: q heads (0..15): bf16 in-place in qb2 (fp32 math).
//       k heads (16..19): fp32 in-place in kbuf (new_k) + bf16 copy to kb2.
// Thread handles d = {2e,2e+1} and {64+2e,64+2e+1}, e in [0,32).
// ---------------------------------------------------------------------------
__global__ __launch_bounds__(256) void rope_kernel(
    uint16_t* __restrict__ qb2, float* __restrict__ kbuf,
    const float* __restrict__ cosb, const float* __restrict__ sinb,
    uint16_t* __restrict__ kb2)
{
    const int idx = blockIdx.x * 256 + threadIdx.x;   // 2*20*2048*32 total
    const int e = idx & 31;
    int t = idx >> 5;
    const int ss = t & 2047; t >>= 11;
    const int h = t % 20, bb = t / 20;
    const float* cp = cosb + ((size_t)bb * Sc + ss) * Dc;
    const float* sp = sinb + ((size_t)bb * Sc + ss) * Dc;
    const float2 c1 = *(const float2*)(cp + 2 * e);
    const float2 c2 = *(const float2*)(cp + 64 + 2 * e);
    const float2 s1 = *(const float2*)(sp + 2 * e);
    const float2 s2 = *(const float2*)(sp + 64 + 2 * e);
    if (h < NQc) {
        const size_t base = (((size_t)(bb * NQc + h) * Sc) + ss) * Dc;
        const uint32_t u1 = *(const uint32_t*)(qb2 + base + 2 * e);
        const uint32_t u2 = *(const uint32_t*)(qb2 + base + 64 + 2 * e);
        const float x1a = bfu2f((uint16_t)u1), x1b = bfu2f((uint16_t)(u1 >> 16));
        const float x2a = bfu2f((uint16_t)u2), x2b = bfu2f((uint16_t)(u2 >> 16));
        const float lo0 = x1a * c1.x - x2a * s1.x, lo1 = x1b * c1.y - x2b * s1.y;
        const float hi0 = x2a * c2.x + x1a * s2.x, hi1 = x2b * c2.y + x1b * s2.y;
        *(uint32_t*)(qb2 + base + 2 * e)      = pk2bf(lo0, lo1);
        *(uint32_t*)(qb2 + base + 64 + 2 * e) = pk2bf(hi0, hi1);
    } else {
        const int hh = h - NQc;
        const size_t base = (((size_t)(bb * NKVc + hh) * Sc) + ss) * Dc;
        const float2 x1 = *(const float2*)(kbuf + base + 2 * e);
        const float2 x2 = *(const float2*)(kbuf + base + 64 + 2 * e);
        const float lo0 = x1.x * c1.x - x2.x * s1.x, lo1 = x1.y * c1.y - x2.y * s1.y;
        const float hi0 = x2.x * c2.x + x1.x * s2.x, hi1 = x2.y * c2.y + x1.y * s2.y;
        *(float2*)(kbuf + base + 2 * e)      = make_float2(lo0, lo1);
        *(float2*)(kbuf + base + 64 + 2 * e) = make_float2(hi0, hi1);
        *(uint32_t*)(kb2 + base + 2 * e)      = pk2bf(lo0, lo1);
        *(uint32_t*)(kb2 + base + 64 + 2 * e) = pk2bf(hi0, hi1);
    }
}

// ---------------------------------------------------------------------------
// V transpose: fp32 V[b][hk][s][d] -> bf16 Vt[b][hk][d][s]  (64s x 128d tiles)
// ---------------------------------------------------------------------------
__global__ __launch_bounds__(256) void vtrans_kernel(
    const float* __restrict__ vbuf, uint16_t* __restrict__ vt)
{
    __shared__ uint16_t T[128][72];
    const int tid = threadIdx.x;
    const int st = blockIdx.x & 31;     // s-tile
    const int bh = blockIdx.x >> 5;     // b*4+hk
    const float* src = vbuf + ((size_t)bh * Sc + st * 64) * Dc;
    #pragma unroll
    for (int i = 0; i < 8; ++i) {
        const int f = tid + 256 * i;            // 2048 float4 per 64x128 tile
        const int s_l = f >> 5, d4 = (f & 31) * 4;
        const float4 v = *((const float4*)(src + (size_t)s_l * Dc) + (f & 31));
        T[d4 + 0][s_l] = f2bf(v.x); T[d4 + 1][s_l] = f2bf(v.y);
        T[d4 + 2][s_l] = f2bf(v.z); T[d4 + 3][s_l] = f2bf(v.w);
    }
    __syncthreads();
    uint16_t* dst = vt + (size_t)bh * Dc * Sc + st * 64;
    #pragma unroll
    for (int i = 0; i < 8; ++i) {
        const int g = tid + 256 * i;            // 2048 uint2: 128 d-rows x 16 chunks
        const int d = g >> 4, s4 = (g & 15) * 4;
        *(uint2*)(dst + (size_t)d * Sc + s4) = *(const uint2*)&T[d][s4];
    }
}

// ---------------------------------------------------------------------------
// Causal GQA flash attention, bf16 MFMA (32x32x16), fp32 softmax.
// Block: 256 thr (4 waves), q-tile 128 rows (32/wave), K-chunks of 64.
// Swapped QK^T (mfma(K,Q) -> S^T) so each lane owns one q-row's stats.
// Q in registers; K [64][128] and Vt [128][64] double-buffered in LDS with
// XOR swizzle (K: slot^=(row&15); Vt: slot^=(d&7)) via pre-swizzled sources.
// P -> A-frags via bf16 pack + shfl_xor(32).
// ---------------------------------------------------------------------------
__global__ __launch_bounds__(256, 2) void attn_kernel(
    const uint16_t* __restrict__ qb, const uint16_t* __restrict__ kb,
    const uint16_t* __restrict__ vt, uint16_t* __restrict__ ab)
{
    __shared__ __align__(16) uint16_t Ks[2][64 * 128];
    __shared__ __align__(16) uint16_t Vs[2][128 * 64];

    const int tid = threadIdx.x, lane = tid & 63, wid = tid >> 6;
    const int qt = 15 - blockIdx.x;            // heavy tiles first
    const int bh = blockIdx.y;
    const int b = bh >> 4, h = bh & 15, hk = h >> 2;
    const int l31 = lane & 31, l5 = lane >> 5;

    const uint16_t* kpB = kb + ((size_t)(b * NKVc + hk) * Sc) * Dc;
    const uint16_t* vpB = vt + ((size_t)(b * NKVc + hk) * Dc) * Sc;

    // Q fragments in registers: B-operand, lane = q-col (l31), k = d
    const uint16_t* qbase =
        qb + (((size_t)(b * NQc + h) * Sc) + qt * 128 + wid * 32 + l31) * Dc;
    bf16x8 qf[8];
    #pragma unroll
    for (int kk = 0; kk < 8; ++kk)
        qf[kk] = *(const bf16x8*)(qbase + kk * 16 + l5 * 8);

    float m_r = -INFINITY, l_r = 0.f;
    f32x16 o0 = {}, o1 = {}, o2 = {}, o3 = {};

    const int qg = qt * 128 + wid * 32 + l31;  // this lane's q row (global)
    const int NCH = 2 * qt + 2;

    auto stage = [&](int ch, int buf) {
        const int kb0 = ch * 64;
        #pragma unroll
        for (int i = 0; i < 4; ++i) {          // K: 16 insts total, 4/wave
            const int g = wid * 4 + i;
            const int row = g * 4 + (lane >> 4);
            const int slot = (lane & 15) ^ (row & 15);
            lds_load16(&Ks[buf][g * 512], kpB + (size_t)(kb0 + row) * Dc + slot * 8);
        }
        #pragma unroll
        for (int i = 0; i < 4; ++i) {          // Vt: 16 insts total, 4/wave
            const int g = wid * 4 + i;
            const int d = g * 8 + (lane >> 3);
            const int slot = (lane & 7) ^ (d & 7);
            lds_load16(&Vs[buf][g * 512], vpB + (size_t)d * Sc + kb0 + slot * 8);
        }
    };

    stage(0, 0);
    __syncthreads();

    for (int ch = 0; ch < NCH; ++ch) {
        const int buf = ch & 1;
        if (ch + 1 < NCH) stage(ch + 1, buf ^ 1);
        const int kb0 = ch * 64;

        // ---- QK^T (S^T): A = K rows, B = Q
        f32x16 s0 = {}, s1 = {};
        #pragma unroll
        for (int kk = 0; kk < 8; ++kk) {
            const int r0 = l31;
            const int sl0 = (kk * 2 + l5) ^ (r0 & 15);
            const bf16x8 a0 = *(const bf16x8*)&Ks[buf][r0 * 128 + sl0 * 8];
            const int r1 = 32 + l31;
            const int sl1 = (kk * 2 + l5) ^ (r1 & 15);
            const bf16x8 a1 = *(const bf16x8*)&Ks[buf][r1 * 128 + sl1 * 8];
            s0 = __builtin_amdgcn_mfma_f32_32x32x16_bf16(a0, qf[kk], s0, 0, 0, 0);
            s1 = __builtin_amdgcn_mfma_f32_32x32x16_bf16(a1, qf[kk], s1, 0, 0, 0);
        }

        // ---- scale + causal mask + online softmax (lane-local q-row)
        float p[32];
        float rm = -INFINITY;
        #pragma unroll
        for (int r = 0; r < 16; ++r) {
            const int krel = (r & 3) + 8 * (r >> 2) + 4 * l5;
            float v0 = s0[r] * SCALE_F;
            float v1 = s1[r] * SCALE_F;
            if (kb0 + krel > qg)      v0 = -INFINITY;
            if (kb0 + 32 + krel > qg) v1 = -INFINITY;
            p[r] = v0; p[16 + r] = v1;
            rm = fmaxf(rm, fmaxf(v0, v1));
        }
        rm = fmaxf(rm, __shfl_xor(rm, 32));
        const float mnew = fmaxf(m_r, rm);
        const float alpha = __expf(m_r - mnew);
        m_r = mnew;

        float sum = 0.f;
        uint32_t pb[16];
        #pragma unroll
        for (int j = 0; j < 8; ++j) {
            const float a0 = __expf(p[2 * j] - mnew),      a1 = __expf(p[2 * j + 1] - mnew);
            const float b0 = __expf(p[16 + 2 * j] - mnew), b1 = __expf(p[16 + 2 * j + 1] - mnew);
            sum += (a0 + a1) + (b0 + b1);
            pb[j]     = pk2bf(a0, a1);
            pb[8 + j] = pk2bf(b0, b1);
        }
        sum += __shfl_xor(sum, 32);
        l_r = l_r * alpha + sum;

        // ---- rescale O (alpha lives at lane q_local; O rows are reg-indexed)
        #pragma unroll
        for (int r = 0; r < 16; ++r) {
            const int qi = (r & 3) + 8 * (r >> 2) + 4 * l5;
            const float av = __shfl(alpha, qi);
            o0[r] *= av; o1[r] *= av; o2[r] *= av; o3[r] *= av;
        }

        // ---- build PV A-fragments (P rows = q, k = keys)
        uint32_t e[16];
        #pragma unroll
        for (int j = 0; j < 16; ++j) e[j] = __shfl_xor(pb[j], 32);
        const bool hi = (l5 == 1);
        const bf16x8 pa0 = hi ? mk8(e[2],  e[3],  pb[2],  pb[3])  : mk8(pb[0],  pb[1],  e[0],  e[1]);   // keys 0-15
        const bf16x8 pa1 = hi ? mk8(e[6],  e[7],  pb[6],  pb[7])  : mk8(pb[4],  pb[5],  e[4],  e[5]);   // keys 16-31
        const bf16x8 pa2 = hi ? mk8(e[10], e[11], pb[10], pb[11]) : mk8(pb[8],  pb[9],  e[8],  e[9]);   // keys 32-47
        const bf16x8 pa3 = hi ? mk8(e[14], e[15], pb[14], pb[15]) : mk8(pb[12], pb[13], e[12], e[13]);  // keys 48-63

        // ---- PV: B = Vt rows (d), k = keys
        #define PV_DV(OO, DV)                                                        \
        {                                                                            \
            const int d = (DV) * 32 + l31;                                           \
            const int rb = d * 64; const int sw = d & 7;                             \
            const bf16x8 b0 = *(const bf16x8*)&Vs[buf][rb + ((0 * 2 + l5) ^ sw) * 8];\
            OO = __builtin_amdgcn_mfma_f32_32x32x16_bf16(pa0, b0, OO, 0, 0, 0);      \
            const bf16x8 b1 = *(const bf16x8*)&Vs[buf][rb + ((1 * 2 + l5) ^ sw) * 8];\
            OO = __builtin_amdgcn_mfma_f32_32x32x16_bf16(pa1, b1, OO, 0, 0, 0);      \
            const bf16x8 b2 = *(const bf16x8*)&Vs[buf][rb + ((2 * 2 + l5) ^ sw) * 8];\
            OO = __builtin_amdgcn_mfma_f32_32x32x16_bf16(pa2, b2, OO, 0, 0, 0);      \
            const bf16x8 b3 = *(const bf16x8*)&Vs[buf][rb + ((3 * 2 + l5) ^ sw) * 8];\
            OO = __builtin_amdgcn_mfma_f32_32x32x16_bf16(pa3, b3, OO, 0, 0, 0);      \
        }
        PV_DV(o0, 0) PV_DV(o1, 1) PV_DV(o2, 2) PV_DV(o3, 3)
        #undef PV_DV

        __syncthreads();
    }

    // ---- epilogue: normalize, write bf16 attn_out [b][s][h*128+d]
    const float inv = 1.f / (l_r + 1e-9f);
    uint16_t* abase = ab + ((size_t)b * Sc) * 2048 + (size_t)h * Dc;
    #pragma unroll
    for (int r = 0; r < 16; ++r) {
        const int qi = (r & 3) + 8 * (r >> 2) + 4 * l5;
        const float iv = __shfl(inv, qi);
        const int srow = qt * 128 + wid * 32 + qi;
        uint16_t* dst = abase + (size_t)srow * 2048 + l31;
        dst[0]  = f2bf(o0[r] * iv);
        dst[32] = f2bf(o1[r] * iv);
        dst[64] = f2bf(o2[r] * iv);
        dst[96] = f2bf(o3[r] * iv);
    }
}

// ---------------------------------------------------------------------------
// Workspace plan (fits the known-safe 32 MiB = 33,554,432 B exactly):
//   [0,16Mi):  xb (bf16 x)          -> dead after gemm_qkv -> ab (attn out)
//   [16,28Mi): wqkv (bf16 weights)  -> dead after gemm_qkv ->
//                 [16,20Mi): kb2 (bf16 rope'd K)
//                 [20,24Mi): vb2t (bf16 V^T)
//   [24,32Mi): wob (bf16 Wo, written after gemm_qkv by cvt2)
// d_out plan:
//   out region [0,32Mi): [0,16Mi) parks bf16 Q (pre->post rope), dead before
//   gemm_out writes fp32 out over the whole region.
// ---------------------------------------------------------------------------
extern "C" void kernel_launch(void* const* d_in, const int* in_sizes, int n_in,
                              void* d_out, int out_size, void* d_ws, size_t ws_size,
                              hipStream_t stream)
{
    const float* x    = (const float*)d_in[0];
    const float* cosb = (const float*)d_in[1];
    const float* sinb = (const float*)d_in[2];
    const float* Wq   = (const float*)d_in[3];
    const float* bq   = (const float*)d_in[4];
    const float* Wk   = (const float*)d_in[5];
    const float* bk   = (const float*)d_in[6];
    const float* Wv   = (const float*)d_in[7];
    const float* bv   = (const float*)d_in[8];
    const float* Wo   = (const float*)d_in[9];

    float* out  = (float*)d_out;                          // [B,S,H] fp32
    float* kout = out  + (size_t)Bc * Sc * Hc;            // new_k fp32
    float* vout = kout + (size_t)Bc * NKVc * Sc * Dc;     // new_v fp32
    uint16_t* qb2 = (uint16_t*)out;                       // bf16 Q parked in out region

    uint8_t* ws = (uint8_t*)d_ws;
    uint16_t* xb   = (uint16_t*)(ws);                     // [0,16Mi)
    uint16_t* wqkv = (uint16_t*)(ws + (16u << 20));       // [16,28Mi)
    uint16_t* kb2  = (uint16_t*)(ws + (16u << 20));       // [16,20Mi) after wqkv dies
    uint16_t* vb2t = (uint16_t*)(ws + (20u << 20));       // [20,24Mi)
    uint16_t* wob  = (uint16_t*)(ws + (24u << 20));       // [24,32Mi)
    uint16_t* ab   = (uint16_t*)(ws);                     // [0,16Mi) after xb dies

    cvt1_kernel<<<2048, 256, 0, stream>>>(x, Wq, Wk, Wv, xb, wqkv);

    gemm_qkv_kernel<<<dim3(32, 24), 256, 0, stream>>>(xb, wqkv, bq, bk, bv,
                                                      qb2, kout, vout);

    rope_kernel<<<10240, 256, 0, stream>>>(qb2, kout, cosb, sinb, kb2);

    vtrans_kernel<<<256, 256, 0, stream>>>(vout, vb2t);

    cvt2_kernel<<<1024, 256, 0, stream>>>(Wo, wob);

    attn_kernel<<<dim3(16, 32), 256, 0, stream>>>(qb2, kb2, vb2t, ab);

    gemm_out_kernel<<<dim3(32, 16), 256, 0, stream>>>(ab, wob, out);
}

// Round 6
// 356.771 us; speedup vs baseline: 6.3291x; 1.0690x over previous
//
#include <hip/hip_runtime.h>
#include <cstdint>
#include <cstddef>
#include <math.h>

// Problem constants
constexpr int Bc   = 2;
constexpr int Sc   = 2048;
constexpr int Hc   = 2048;
constexpr int NQc  = 16;
constexpr int NKVc = 4;
constexpr int Dc   = 128;
#define SCALE_F 0.08838834764831845f   // 1/sqrt(128)

typedef __attribute__((ext_vector_type(8))) short  bf16x8;
typedef __attribute__((ext_vector_type(4))) float  f32x4;
typedef __attribute__((ext_vector_type(16))) float f32x16;

// ---- helpers ---------------------------------------------------------------
__device__ __forceinline__ uint16_t f2bf(float f) {
    union { float f; uint32_t u; } v; v.f = f;
    uint32_t u = v.u;
    return (uint16_t)((u + 0x7FFFu + ((u >> 16) & 1u)) >> 16);   // RNE
}
__device__ __forceinline__ uint32_t pk2bf(float lo, float hi) {
    return (uint32_t)f2bf(lo) | ((uint32_t)f2bf(hi) << 16);
}
__device__ __forceinline__ float bfu2f(uint16_t u) {
    union { uint32_t u; float f; } v; v.u = (uint32_t)u << 16; return v.f;
}
// async global->LDS, 16B per lane; lds base must be wave-uniform (HW adds lane*16)
__device__ __forceinline__ void lds_load16(void* lds, const void* g) {
    __builtin_amdgcn_global_load_lds(
        (const __attribute__((address_space(1))) uint32_t*)g,
        (__attribute__((address_space(3))) uint32_t*)lds, 16, 0, 0);
}
__device__ __forceinline__ bf16x8 mk8(uint32_t w0, uint32_t w1, uint32_t w2, uint32_t w3) {
    union { uint32_t u[4]; bf16x8 s; } t;
    t.u[0] = w0; t.u[1] = w1; t.u[2] = w2; t.u[3] = w3; return t.s;
}

// ---------------------------------------------------------------------------
// cvt1: f32 -> bf16 for x -> xb and [Wq;Wk;Wv] -> wqkv[3072][2048]
// ---------------------------------------------------------------------------
__global__ __launch_bounds__(256) void cvt1_kernel(
    const float* __restrict__ x,  const float* __restrict__ wq,
    const float* __restrict__ wk, const float* __restrict__ wv,
    uint16_t* __restrict__ xb, uint16_t* __restrict__ wqkv)
{
    const long long TOT = 3670016LL;  // total float4 count
    for (long long i = (long long)blockIdx.x * 256 + threadIdx.x; i < TOT;
         i += (long long)gridDim.x * 256) {
        const float* src; uint16_t* dst; long long off;
        if (i < 2097152LL)      { src = x;  dst = xb;             off = i; }
        else if (i < 3145728LL) { src = wq; dst = wqkv;           off = i - 2097152LL; }
        else if (i < 3407872LL) { src = wk; dst = wqkv + 4194304; off = i - 3145728LL; }
        else                    { src = wv; dst = wqkv + 5242880; off = i - 3407872LL; }
        float4 v = *((const float4*)src + off);
        uint2 o; o.x = pk2bf(v.x, v.y); o.y = pk2bf(v.z, v.w);
        *((uint2*)dst + off) = o;
    }
}

// cvt2: Wo -> bf16 (runs after wqkv region is dead)
__global__ __launch_bounds__(256) void cvt2_kernel(
    const float* __restrict__ wo, uint16_t* __restrict__ wob)
{
    for (long long i = (long long)blockIdx.x * 256 + threadIdx.x; i < 1048576LL;
         i += (long long)gridDim.x * 256) {
        float4 v = *((const float4*)wo + i);
        uint2 o; o.x = pk2bf(v.x, v.y); o.y = pk2bf(v.z, v.w);
        *((uint2*)wob + i) = o;
    }
}

// ---------------------------------------------------------------------------
// Shared GEMM pieces: 128x128 tile, BK=64, 4 waves (2x2 of 64x64), 16x16x32 MFMA.
// LDS tiles [128 rows][64 bf16] with XOR swizzle: 16B-slot ^= (row&7); staged via
// global_load_lds with inverse-swizzled per-lane SOURCE (rule 21), LDS linear.
// ---------------------------------------------------------------------------
__device__ __forceinline__ void gemm_stage(const uint16_t* __restrict__ src,
                                           size_t row_stride, uint16_t* lds,
                                           int wid, int lane)
{
    #pragma unroll
    for (int i = 0; i < 4; ++i) {
        const int g = wid * 4 + i;               // 16 insts per tile, 4/wave
        const int r = g * 8 + (lane >> 3);       // 8 rows per inst (128B rows)
        const int slot = (lane & 7) ^ (r & 7);   // inverse-swizzled source slot
        lds_load16(lds + g * 512, src + (size_t)r * row_stride + slot * 8);
    }
}

#define GEMM_CORE(AS, BS, AB, BB)                                              \
    f32x4 acc[4][4] = {};                                                      \
    gemm_stage(AB, 2048, &AS[0][0], wid, lane);                                \
    gemm_stage(BB, 2048, &BS[0][0], wid, lane);                                \
    __syncthreads();                                                           \
    for (int t = 0; t < 32; ++t) {                                             \
        const int cur = t & 1;                                                 \
        if (t + 1 < 32) {                                                      \
            gemm_stage(AB + (t + 1) * 64, 2048, &AS[cur ^ 1][0], wid, lane);   \
            gemm_stage(BB + (t + 1) * 64, 2048, &BS[cur ^ 1][0], wid, lane);   \
        }                                                                      \
        _Pragma("unroll")                                                      \
        for (int kk = 0; kk < 2; ++kk) {                                       \
            bf16x8 av[4], bw[4];                                               \
            _Pragma("unroll")                                                  \
            for (int mi = 0; mi < 4; ++mi) {                                   \
                const int row = wr * 64 + mi * 16 + (lane & 15);               \
                const int slot = (kk * 4 + (lane >> 4)) ^ (row & 7);           \
                av[mi] = *(const bf16x8*)&AS[cur][row * 64 + slot * 8];        \
            }                                                                  \
            _Pragma("unroll")                                                  \
            for (int nj = 0; nj < 4; ++nj) {                                   \
                const int row = wc * 64 + nj * 16 + (lane & 15);               \
                const int slot = (kk * 4 + (lane >> 4)) ^ (row & 7);           \
                bw[nj] = *(const bf16x8*)&BS[cur][row * 64 + slot * 8];        \
            }                                                                  \
            _Pragma("unroll")                                                  \
            for (int mi = 0; mi < 4; ++mi)                                     \
                _Pragma("unroll")                                              \
                for (int nj = 0; nj < 4; ++nj)                                 \
                    acc[mi][nj] = __builtin_amdgcn_mfma_f32_16x16x32_bf16(     \
                        av[mi], bw[nj], acc[mi][nj], 0, 0, 0);                 \
        }                                                                      \
        __syncthreads();                                                       \
    }

// GEMM1: [4096,2048]bf16 @ wqkv[3072,2048]^T + bias
//   q cols -> bf16 qb2 [b][h][s][d]  (pre-rope; rope applied in-place later)
//   k cols -> fp32 kbuf (new_k, pre-rope; rope in-place later)
//   v cols -> fp32 vbuf (new_v, final)
__global__ __launch_bounds__(256) void gemm_qkv_kernel(
    const uint16_t* __restrict__ xb, const uint16_t* __restrict__ wqkv,
    const float* __restrict__ bq, const float* __restrict__ bk, const float* __restrict__ bv,
    uint16_t* __restrict__ qb2, float* __restrict__ kbuf, float* __restrict__ vbuf)
{
    __shared__ __align__(16) uint16_t As[2][128 * 64];
    __shared__ __align__(16) uint16_t Bs[2][128 * 64];
    const int tid = threadIdx.x, lane = tid & 63, wid = tid >> 6;
    const int m0 = blockIdx.x * 128, n0 = blockIdx.y * 128;
    const int wr = wid >> 1, wc = wid & 1;
    const uint16_t* Ab = xb + (size_t)m0 * 2048;
    const uint16_t* Bb = wqkv + (size_t)n0 * 2048;

    GEMM_CORE(As, Bs, Ab, Bb)

    const float* bias; int rtype; int nbase;
    if (n0 < 2048)      { bias = bq + n0;          rtype = 0; nbase = n0; }
    else if (n0 < 2560) { bias = bk + (n0 - 2048); rtype = 1; nbase = n0 - 2048; }
    else                { bias = bv + (n0 - 2560); rtype = 2; nbase = n0 - 2560; }
    #pragma unroll
    for (int mi = 0; mi < 4; ++mi) {
        #pragma unroll
        for (int nj = 0; nj < 4; ++nj) {
            const int ct = wc * 64 + nj * 16 + (lane & 15);  // tile-local col
            const int nloc = nbase + ct;
            const int head = nloc >> 7, d = nloc & 127;
            const float bval = bias[ct];
            #pragma unroll
            for (int j = 0; j < 4; ++j) {
                const int m = m0 + wr * 64 + mi * 16 + (lane >> 4) * 4 + j;
                const int bb2 = m >> 11, ss = m & 2047;
                const float v = acc[mi][nj][j] + bval;
                if (rtype == 0)
                    qb2[(((size_t)(bb2 * NQc + head) * Sc) + ss) * Dc + d] = f2bf(v);
                else if (rtype == 1)
                    kbuf[(((size_t)(bb2 * NKVc + head) * Sc) + ss) * Dc + d] = v;
                else
                    vbuf[(((size_t)(bb2 * NKVc + head) * Sc) + ss) * Dc + d] = v;
            }
        }
    }
}

// GEMM2: attn_out[4096,2048]bf16 @ Wo[2048,2048]^T -> out fp32
__global__ __launch_bounds__(256) void gemm_out_kernel(
    const uint16_t* __restrict__ ab, const uint16_t* __restrict__ wob,
    float* __restrict__ C)
{
    __shared__ __align__(16) uint16_t As[2][128 * 64];
    __shared__ __align__(16) uint16_t Bs[2][128 * 64];
    const int tid = threadIdx.x, lane = tid & 63, wid = tid >> 6;
    const int m0 = blockIdx.x * 128, n0 = blockIdx.y * 128;
    const int wr = wid >> 1, wc = wid & 1;
    const uint16_t* Ab = ab + (size_t)m0 * 2048;
    const uint16_t* Bb = wob + (size_t)n0 * 2048;

    GEMM_CORE(As, Bs, Ab, Bb)

    #pragma unroll
    for (int mi = 0; mi < 4; ++mi) {
        #pragma unroll
        for (int nj = 0; nj < 4; ++nj) {
            const int n = n0 + wc * 64 + nj * 16 + (lane & 15);
            #pragma unroll
            for (int j = 0; j < 4; ++j) {
                const int m = m0 + wr * 64 + mi * 16 + (lane >> 4) * 4 + j;
                C[(size_t)m * 2048 + n] = acc[mi][nj][j];
            }
        }
    }
}

// ---------------------------------------------------------------------------
// RoPE: q heads (0..15): bf16 in-place in qb2 (fp32 math).
//       k heads (16..19): fp32 in-place in kbuf (new_k) + bf16 copy to kb2.
// ---------------------------------------------------------------------------
__global__ __launch_bounds__(256) void rope_kernel(
    uint16_t* __restrict__ qb2, float* __restrict__ kbuf,
    const float* __restrict__ cosb, const float* __restrict__ sinb,
    uint16_t* __restrict__ kb2)
{
    const int idx = blockIdx.x * 256 + threadIdx.x;   // 2*20*2048*32 total
    const int e = idx & 31;
    int t = idx >> 5;
    const int ss = t & 2047; t >>= 11;
    const int h = t % 20, bb = t / 20;
    const float* cp = cosb + ((size_t)bb * Sc + ss) * Dc;
    const float* sp = sinb + ((size_t)bb * Sc + ss) * Dc;
    const float2 c1 = *(const float2*)(cp + 2 * e);
    const float2 c2 = *(const float2*)(cp + 64 + 2 * e);
    const float2 s1 = *(const float2*)(sp + 2 * e);
    const float2 s2 = *(const float2*)(sp + 64 + 2 * e);
    if (h < NQc) {
        const size_t base = (((size_t)(bb * NQc + h) * Sc) + ss) * Dc;
        const uint32_t u1 = *(const uint32_t*)(qb2 + base + 2 * e);
        const uint32_t u2 = *(const uint32_t*)(qb2 + base + 64 + 2 * e);
        const float x1a = bfu2f((uint16_t)u1), x1b = bfu2f((uint16_t)(u1 >> 16));
        const float x2a = bfu2f((uint16_t)u2), x2b = bfu2f((uint16_t)(u2 >> 16));
        const float lo0 = x1a * c1.x - x2a * s1.x, lo1 = x1b * c1.y - x2b * s1.y;
        const float hi0 = x2a * c2.x + x1a * s2.x, hi1 = x2b * c2.y + x1b * s2.y;
        *(uint32_t*)(qb2 + base + 2 * e)      = pk2bf(lo0, lo1);
        *(uint32_t*)(qb2 + base + 64 + 2 * e) = pk2bf(hi0, hi1);
    } else {
        const int hh = h - NQc;
        const size_t base = (((size_t)(bb * NKVc + hh) * Sc) + ss) * Dc;
        const float2 x1 = *(const float2*)(kbuf + base + 2 * e);
        const float2 x2 = *(const float2*)(kbuf + base + 64 + 2 * e);
        const float lo0 = x1.x * c1.x - x2.x * s1.x, lo1 = x1.y * c1.y - x2.y * s1.y;
        const float hi0 = x2.x * c2.x + x1.x * s2.x, hi1 = x2.y * c2.y + x1.y * s2.y;
        *(float2*)(kbuf + base + 2 * e)      = make_float2(lo0, lo1);
        *(float2*)(kbuf + base + 64 + 2 * e) = make_float2(hi0, hi1);
        *(uint32_t*)(kb2 + base + 2 * e)      = pk2bf(lo0, lo1);
        *(uint32_t*)(kb2 + base + 64 + 2 * e) = pk2bf(hi0, hi1);
    }
}

// ---------------------------------------------------------------------------
// V transpose: fp32 V[b][hk][s][d] -> bf16 Vt[b][hk][d][s]  (64s x 128d tiles)
// ---------------------------------------------------------------------------
__global__ __launch_bounds__(256) void vtrans_kernel(
    const float* __restrict__ vbuf, uint16_t* __restrict__ vt)
{
    __shared__ uint16_t T[128][72];
    const int tid = threadIdx.x;
    const int st = blockIdx.x & 31;     // s-tile
    const int bh = blockIdx.x >> 5;     // b*4+hk
    const float* src = vbuf + ((size_t)bh * Sc + st * 64) * Dc;
    #pragma unroll
    for (int i = 0; i < 8; ++i) {
        const int f = tid + 256 * i;            // 2048 float4 per 64x128 tile
        const int s_l = f >> 5, d4 = (f & 31) * 4;
        const float4 v = *((const float4*)(src + (size_t)s_l * Dc) + (f & 31));
        T[d4 + 0][s_l] = f2bf(v.x); T[d4 + 1][s_l] = f2bf(v.y);
        T[d4 + 2][s_l] = f2bf(v.z); T[d4 + 3][s_l] = f2bf(v.w);
    }
    __syncthreads();
    uint16_t* dst = vt + (size_t)bh * Dc * Sc + st * 64;
    #pragma unroll
    for (int i = 0; i < 8; ++i) {
        const int g = tid + 256 * i;            // 2048 uint2: 128 d-rows x 16 chunks
        const int d = g >> 4, s4 = (g & 15) * 4;
        *(uint2*)(dst + (size_t)d * Sc + s4) = *(const uint2*)&T[d][s4];
    }
}

// ---------------------------------------------------------------------------
// Causal GQA flash attention, bf16 MFMA (32x32x16), fp32 softmax (log2 domain).
// 1-D grid of 512 blocks; complementary (qt, 15-qt) mapping so blocks k and
// k+256 (same CU under breadth-first dispatch at 2 blocks/CU) sum to a
// constant 34 chunks -> balanced CU load.
// Block: 256 thr (4 waves), q-tile 128 rows (32/wave), K-chunks of 64.
// Swapped QK^T (mfma(K,Q) -> S^T) so each lane owns one q-row's stats.
// Q in registers; K [64][128] and Vt [128][64] double-buffered in LDS with
// XOR swizzle via pre-swizzled global_load_lds sources.
// P -> A-frags via v_cvt_pk_bf16_f32 + v_permlane32_swap_b32 (T12).
// Defer-rescale threshold 8 (log2 domain) skips O-rescale most chunks (T13).
// ---------------------------------------------------------------------------
__global__ __launch_bounds__(256, 2) void attn_kernel(
    const uint16_t* __restrict__ qb, const uint16_t* __restrict__ kb,
    const uint16_t* __restrict__ vt, uint16_t* __restrict__ ab)
{
    __shared__ __align__(16) uint16_t Ks[2][64 * 128];
    __shared__ __align__(16) uint16_t Vs[2][128 * 64];

    const int tid = threadIdx.x, lane = tid & 63, wid = tid >> 6;
    const int lin = blockIdx.x;
    const int hf = lin >> 8, pp = lin & 255;
    const int qt = hf ? (pp & 15) : (15 - (pp & 15));   // complementary pairing
    const int bh = (pp >> 4) + hf * 16;
    const int b = bh >> 4, h = bh & 15, hk = h >> 2;
    const int l31 = lane & 31, l5 = lane >> 5;

    const uint16_t* kpB = kb + ((size_t)(b * NKVc + hk) * Sc) * Dc;
    const uint16_t* vpB = vt + ((size_t)(b * NKVc + hk) * Dc) * Sc;

    // Q fragments in registers: B-operand, lane = q-col (l31), k = d
    const uint16_t* qbase =
        qb + (((size_t)(b * NQc + h) * Sc) + qt * 128 + wid * 32 + l31) * Dc;
    bf16x8 qf[8];
    #pragma unroll
    for (int kk = 0; kk < 8; ++kk)
        qf[kk] = *(const bf16x8*)(qbase + kk * 16 + l5 * 8);

    float m_r = -INFINITY, l_r = 0.f;
    f32x16 o0 = {}, o1 = {}, o2 = {}, o3 = {};

    const int qg      = qt * 128 + wid * 32 + l31;  // this lane's q row
    const int qgw_min = qt * 128 + wid * 32;        // wave's min q row
    const int qgw_max = qgw_min + 31;               // wave's max q row
    const int NCH = 2 * qt + 2;
    constexpr float SCL2 = 0.08838834764831845f * 1.4426950408889634f; // SCALE*log2e

    auto stage = [&](int ch, int buf) {
        const int kb0 = ch * 64;
        #pragma unroll
        for (int i = 0; i < 4; ++i) {          // K: 16 insts total, 4/wave
            const int g = wid * 4 + i;
            const int row = g * 4 + (lane >> 4);
            const int slot = (lane & 15) ^ (row & 15);
            lds_load16(&Ks[buf][g * 512], kpB + (size_t)(kb0 + row) * Dc + slot * 8);
        }
        #pragma unroll
        for (int i = 0; i < 4; ++i) {          // Vt: 16 insts total, 4/wave
            const int g = wid * 4 + i;
            const int d = g * 8 + (lane >> 3);
            const int slot = (lane & 7) ^ (d & 7);
            lds_load16(&Vs[buf][g * 512], vpB + (size_t)d * Sc + kb0 + slot * 8);
        }
    };

    stage(0, 0);
    __syncthreads();

    for (int ch = 0; ch < NCH; ++ch) {
        const int buf = ch & 1;
        if (ch + 1 < NCH) stage(ch + 1, buf ^ 1);
        const int kb0 = ch * 64;

        if (kb0 <= qgw_max) {   // wave-uniform: skip fully-masked chunks
            // ---- QK^T (S^T): A = K rows, B = Q
            f32x16 s0 = {}, s1 = {};
            __builtin_amdgcn_s_setprio(1);
            #pragma unroll
            for (int kk = 0; kk < 8; ++kk) {
                const int r0 = l31;
                const int sl0 = (kk * 2 + l5) ^ (r0 & 15);
                const bf16x8 a0 = *(const bf16x8*)&Ks[buf][r0 * 128 + sl0 * 8];
                const int r1 = 32 + l31;
                const int sl1 = (kk * 2 + l5) ^ (r1 & 15);
                const bf16x8 a1 = *(const bf16x8*)&Ks[buf][r1 * 128 + sl1 * 8];
                s0 = __builtin_amdgcn_mfma_f32_32x32x16_bf16(a0, qf[kk], s0, 0, 0, 0);
                s1 = __builtin_amdgcn_mfma_f32_32x32x16_bf16(a1, qf[kk], s1, 0, 0, 0);
            }
            __builtin_amdgcn_s_setprio(0);

            // ---- logits in log2 domain; mask only when the chunk can cross
            float p[32];
            const bool needmask = (kb0 + 63 > qgw_min);
            #pragma unroll
            for (int r = 0; r < 16; ++r) {
                float v0 = s0[r] * SCL2;
                float v1 = s1[r] * SCL2;
                if (needmask) {
                    const int krel = (r & 3) + 8 * (r >> 2) + 4 * l5;
                    if (kb0 + krel > qg)      v0 = -INFINITY;
                    if (kb0 + 32 + krel > qg) v1 = -INFINITY;
                }
                p[r] = v0; p[16 + r] = v1;
            }
            // ---- tree max (depth 5) + cross-half
            float tm[16];
            #pragma unroll
            for (int i = 0; i < 16; ++i) tm[i] = fmaxf(p[i], p[16 + i]);
            #pragma unroll
            for (int i = 0; i < 8; ++i) tm[i] = fmaxf(tm[i], tm[8 + i]);
            #pragma unroll
            for (int i = 0; i < 4; ++i) tm[i] = fmaxf(tm[i], tm[4 + i]);
            float rm = fmaxf(fmaxf(tm[0], tm[1]), fmaxf(tm[2], tm[3]));
            rm = fmaxf(rm, __shfl_xor(rm, 32));

            // ---- defer-rescale (T13): skip O-rescale unless max grew > 8
            if (!__all(rm <= m_r + 8.0f)) {
                const float mnew = fmaxf(m_r, rm);
                const float alpha = exp2f(m_r - mnew);
                #pragma unroll
                for (int r = 0; r < 16; ++r) {
                    const int qi = (r & 3) + 8 * (r >> 2) + 4 * l5;
                    const float av = __shfl(alpha, qi);
                    o0[r] *= av; o1[r] *= av; o2[r] *= av; o3[r] *= av;
                }
                l_r *= alpha;
                m_r = mnew;
            }

            // ---- exponentials (bounded by 2^8 under defer) + tree sum
            #pragma unroll
            for (int j = 0; j < 32; ++j) p[j] = exp2f(p[j] - m_r);
            float s8[8];
            #pragma unroll
            for (int i = 0; i < 8; ++i)
                s8[i] = (p[i] + p[8 + i]) + (p[16 + i] + p[24 + i]);
            float sum = ((s8[0] + s8[1]) + (s8[2] + s8[3]))
                      + ((s8[4] + s8[5]) + (s8[6] + s8[7]));
            sum += __shfl_xor(sum, 32);
            l_r += sum;

            // ---- pack P to bf16 pairs (RNE) with v_cvt_pk
            uint32_t pb[16];
            #pragma unroll
            for (int j = 0; j < 8; ++j) {
                asm("v_cvt_pk_bf16_f32 %0, %1, %2"
                    : "=v"(pb[j]) : "v"(p[2 * j]), "v"(p[2 * j + 1]));
                asm("v_cvt_pk_bf16_f32 %0, %1, %2"
                    : "=v"(pb[8 + j]) : "v"(p[16 + 2 * j]), "v"(p[16 + 2 * j + 1]));
            }
            // ---- build PV A-frags: swap(pb[4g],pb[4g+2]) -> words 0,2;
            //      swap(pb[4g+1],pb[4g+3]) -> words 1,3  (verified lane algebra)
            #pragma unroll
            for (int g2 = 0; g2 < 4; ++g2) {
                asm("v_permlane32_swap_b32 %0, %1"
                    : "+v"(pb[4 * g2 + 0]), "+v"(pb[4 * g2 + 2]));
                asm("v_permlane32_swap_b32 %0, %1"
                    : "+v"(pb[4 * g2 + 1]), "+v"(pb[4 * g2 + 3]));
            }
            const bf16x8 pa0 = mk8(pb[0],  pb[1],  pb[2],  pb[3]);
            const bf16x8 pa1 = mk8(pb[4],  pb[5],  pb[6],  pb[7]);
            const bf16x8 pa2 = mk8(pb[8],  pb[9],  pb[10], pb[11]);
            const bf16x8 pa3 = mk8(pb[12], pb[13], pb[14], pb[15]);

            // ---- PV: B = Vt rows (d), k = keys
            __builtin_amdgcn_s_setprio(1);
            #define PV_DV(OO, DV)                                                        \
            {                                                                            \
                const int d = (DV) * 32 + l31;                                           \
                const int rb = d * 64; const int sw = d & 7;                             \
                const bf16x8 b0 = *(const bf16x8*)&Vs[buf][rb + ((0 * 2 + l5) ^ sw) * 8];\
                OO = __builtin_amdgcn_mfma_f32_32x32x16_bf16(pa0, b0, OO, 0, 0, 0);      \
                const bf16x8 b1 = *(const bf16x8*)&Vs[buf][rb + ((1 * 2 + l5) ^ sw) * 8];\
                OO = __builtin_amdgcn_mfma_f32_32x32x16_bf16(pa1, b1, OO, 0, 0, 0);      \
                const bf16x8 b2 = *(const bf16x8*)&Vs[buf][rb + ((2 * 2 + l5) ^ sw) * 8];\
                OO = __builtin_amdgcn_mfma_f32_32x32x16_bf16(pa2, b2, OO, 0, 0, 0);      \
                const bf16x8 b3 = *(const bf16x8*)&Vs[buf][rb + ((3 * 2 + l5) ^ sw) * 8];\
                OO = __builtin_amdgcn_mfma_f32_32x32x16_bf16(pa3, b3, OO, 0, 0, 0);      \
            }
            PV_DV(o0, 0) PV_DV(o1, 1) PV_DV(o2, 2) PV_DV(o3, 3)
            #undef PV_DV
            __builtin_amdgcn_s_setprio(0);
        }

        __syncthreads();
    }

    // ---- epilogue: normalize, write bf16 attn_out [b][s][h*128+d]
    const float inv = 1.f / (l_r + 1e-9f);
    uint16_t* abase = ab + ((size_t)b * Sc) * 2048 + (size_t)h * Dc;
    #pragma unroll
    for (int r = 0; r < 16; ++r) {
        const int qi = (r & 3) + 8 * (r >> 2) + 4 * l5;
        const float iv = __shfl(inv, qi);
        const int srow = qt * 128 + wid * 32 + qi;
        uint16_t* dst = abase + (size_t)srow * 2048 + l31;
        dst[0]  = f2bf(o0[r] * iv);
        dst[32] = f2bf(o1[r] * iv);
        dst[64] = f2bf(o2[r] * iv);
        dst[96] = f2bf(o3[r] * iv);
    }
}

// ---------------------------------------------------------------------------
// Workspace plan (fits the known-safe 32 MiB):
//   [0,16Mi):  xb -> dead after gemm_qkv -> ab
//   [16,28Mi): wqkv -> dead after gemm_qkv -> kb2 [16,20Mi) + vb2t [20,24Mi)
//   [24,32Mi): wob (written by cvt2 after gemm_qkv)
// d_out: [0,16Mi) parks bf16 Q until gemm_out overwrites with fp32 out.
// ---------------------------------------------------------------------------
extern "C" void kernel_launch(void* const* d_in, const int* in_sizes, int n_in,
                              void* d_out, int out_size, void* d_ws, size_t ws_size,
                              hipStream_t stream)
{
    const float* x    = (const float*)d_in[0];
    const float* cosb = (const float*)d_in[1];
    const float* sinb = (const float*)d_in[2];
    const float* Wq   = (const float*)d_in[3];
    const float* bq   = (const float*)d_in[4];
    const float* Wk   = (const float*)d_in[5];
    const float* bk   = (const float*)d_in[6];
    const float* Wv   = (const float*)d_in[7];
    const float* bv   = (const float*)d_in[8];
    const float* Wo   = (const float*)d_in[9];

    float* out  = (float*)d_out;                          // [B,S,H] fp32
    float* kout = out  + (size_t)Bc * Sc * Hc;            // new_k fp32
    float* vout = kout + (size_t)Bc * NKVc * Sc * Dc;     // new_v fp32
    uint16_t* qb2 = (uint16_t*)out;                       // bf16 Q parked in out region

    uint8_t* ws = (uint8_t*)d_ws;
    uint16_t* xb   = (uint16_t*)(ws);                     // [0,16Mi)
    uint16_t* wqkv = (uint16_t*)(ws + (16u << 20));       // [16,28Mi)
    uint16_t* kb2  = (uint16_t*)(ws + (16u << 20));       // [16,20Mi) after wqkv dies
    uint16_t* vb2t = (uint16_t*)(ws + (20u << 20));       // [20,24Mi)
    uint16_t* wob  = (uint16_t*)(ws + (24u << 20));       // [24,32Mi)
    uint16_t* ab   = (uint16_t*)(ws);                     // [0,16Mi) after xb dies

    cvt1_kernel<<<2048, 256, 0, stream>>>(x, Wq, Wk, Wv, xb, wqkv);

    gemm_qkv_kernel<<<dim3(32, 24), 256, 0, stream>>>(xb, wqkv, bq, bk, bv,
                                                      qb2, kout, vout);

    rope_kernel<<<10240, 256, 0, stream>>>(qb2, kout, cosb, sinb, kb2);

    vtrans_kernel<<<256, 256, 0, stream>>>(vout, vb2t);

    cvt2_kernel<<<1024, 256, 0, stream>>>(Wo, wob);

    attn_kernel<<<512, 256, 0, stream>>>(qb2, kb2, vb2t, ab);

    gemm_out_kernel<<<dim3(32, 16), 256, 0, stream>>>(ab, wob, out);
}

// Round 7
// 354.708 us; speedup vs baseline: 6.3660x; 1.0058x over previous
//
#include <hip/hip_runtime.h>
#include <cstdint>
#include <cstddef>
#include <math.h>

// Problem constants
constexpr int Bc   = 2;
constexpr int Sc   = 2048;
constexpr int Hc   = 2048;
constexpr int NQc  = 16;
constexpr int NKVc = 4;
constexpr int Dc   = 128;
#define SCALE_F 0.08838834764831845f   // 1/sqrt(128)

typedef __attribute__((ext_vector_type(8))) short  bf16x8;
typedef __attribute__((ext_vector_type(4))) float  f32x4;
typedef __attribute__((ext_vector_type(16))) float f32x16;

// ---- helpers ---------------------------------------------------------------
__device__ __forceinline__ uint16_t f2bf(float f) {
    union { float f; uint32_t u; } v; v.f = f;
    uint32_t u = v.u;
    return (uint16_t)((u + 0x7FFFu + ((u >> 16) & 1u)) >> 16);   // RNE
}
__device__ __forceinline__ uint32_t pk2bf(float lo, float hi) {
    return (uint32_t)f2bf(lo) | ((uint32_t)f2bf(hi) << 16);
}
__device__ __forceinline__ float bfu2f(uint16_t u) {
    union { uint32_t u; float f; } v; v.u = (uint32_t)u << 16; return v.f;
}
// async global->LDS, 16B per lane; lds base must be wave-uniform (HW adds lane*16)
__device__ __forceinline__ void lds_load16(void* lds, const void* g) {
    __builtin_amdgcn_global_load_lds(
        (const __attribute__((address_space(1))) uint32_t*)g,
        (__attribute__((address_space(3))) uint32_t*)lds, 16, 0, 0);
}
__device__ __forceinline__ bf16x8 mk8(uint32_t w0, uint32_t w1, uint32_t w2, uint32_t w3) {
    union { uint32_t u[4]; bf16x8 s; } t;
    t.u[0] = w0; t.u[1] = w1; t.u[2] = w2; t.u[3] = w3; return t.s;
}

// ---------------------------------------------------------------------------
// cvt1: f32 -> bf16 for x -> xb and [Wq;Wk;Wv] -> wqkv[3072][2048]
// ---------------------------------------------------------------------------
__global__ __launch_bounds__(256) void cvt1_kernel(
    const float* __restrict__ x,  const float* __restrict__ wq,
    const float* __restrict__ wk, const float* __restrict__ wv,
    uint16_t* __restrict__ xb, uint16_t* __restrict__ wqkv)
{
    const long long TOT = 3670016LL;  // total float4 count
    for (long long i = (long long)blockIdx.x * 256 + threadIdx.x; i < TOT;
         i += (long long)gridDim.x * 256) {
        const float* src; uint16_t* dst; long long off;
        if (i < 2097152LL)      { src = x;  dst = xb;             off = i; }
        else if (i < 3145728LL) { src = wq; dst = wqkv;           off = i - 2097152LL; }
        else if (i < 3407872LL) { src = wk; dst = wqkv + 4194304; off = i - 3145728LL; }
        else                    { src = wv; dst = wqkv + 5242880; off = i - 3407872LL; }
        float4 v = *((const float4*)src + off);
        uint2 o; o.x = pk2bf(v.x, v.y); o.y = pk2bf(v.z, v.w);
        *((uint2*)dst + off) = o;
    }
}

// cvt2: Wo -> bf16 (runs after wqkv region is dead)
__global__ __launch_bounds__(256) void cvt2_kernel(
    const float* __restrict__ wo, uint16_t* __restrict__ wob)
{
    for (long long i = (long long)blockIdx.x * 256 + threadIdx.x; i < 1048576LL;
         i += (long long)gridDim.x * 256) {
        float4 v = *((const float4*)wo + i);
        uint2 o; o.x = pk2bf(v.x, v.y); o.y = pk2bf(v.z, v.w);
        *((uint2*)wob + i) = o;
    }
}

// ---------------------------------------------------------------------------
// 256x256 GEMM, BK=64, 8 waves (2M x 4N), 512 thr, 16x16x32 MFMA.
// LDS: 2 slots x (A[256][64] + B[256][64]) bf16 = 128 KB, 1 block/CU.
// XOR swizzle: 16B-slot ^= (row&7) (8-way spread, 2-way=free on ds_read_b128);
// staged via global_load_lds with inverse-swizzled per-lane SOURCE (rule 21).
// Pipeline: stage tile t+1 into the DEAD slot right after tile-t's top barrier;
// vmcnt(0) at top waits loads issued one full tile earlier (near-zero stall,
// no mid-flight drain). Raw s_barrier + sched_barrier fences. Races audited:
//   RAW: wave's own loads waited (vmcnt) BEFORE shared barrier -> all visible.
//   WAR: writes to slot X issued only after the barrier following the last
//        reads of X (tile t-1's reads complete at its lgkmcnt before barrier).
// ---------------------------------------------------------------------------
__device__ __forceinline__ void stage256(const uint16_t* __restrict__ Ab,
                                         const uint16_t* __restrict__ Bb,
                                         int koff, uint16_t* sA, uint16_t* sB,
                                         int wid, int lane)
{
    #pragma unroll
    for (int i = 0; i < 8; ++i) {
        const int g = wid * 8 + i;            // 64 insts: 32 A + 32 B
        if (g < 32) {
            const int r = g * 8 + (lane >> 3);
            lds_load16(sA + g * 512,
                       Ab + (size_t)r * 2048 + koff + (((lane & 7) ^ (r & 7)) * 8));
        } else {
            const int gb = g - 32;
            const int r = gb * 8 + (lane >> 3);
            lds_load16(sB + gb * 512,
                       Bb + (size_t)r * 2048 + koff + (((lane & 7) ^ (r & 7)) * 8));
        }
    }
}

#define GEMM256_CORE(SA, SB, AB, BB)                                            \
    f32x4 acc[8][4] = {};                                                       \
    stage256(AB, BB, 0, &SA[0][0], &SB[0][0], wid, lane);                       \
    for (int t = 0; t < 32; ++t) {                                              \
        const int cur = t & 1;                                                  \
        asm volatile("s_waitcnt vmcnt(0)" ::: "memory");                        \
        __builtin_amdgcn_sched_barrier(0);                                      \
        __builtin_amdgcn_s_barrier();                                           \
        __builtin_amdgcn_sched_barrier(0);                                      \
        if (t + 1 < 32)                                                         \
            stage256(AB, BB, (t + 1) * 64, &SA[cur ^ 1][0], &SB[cur ^ 1][0],    \
                     wid, lane);                                                \
        _Pragma("unroll")                                                       \
        for (int kk = 0; kk < 2; ++kk) {                                        \
            bf16x8 av[8], bw[4];                                                \
            _Pragma("unroll")                                                   \
            for (int mi = 0; mi < 8; ++mi) {                                    \
                const int row = wr * 128 + mi * 16 + (lane & 15);               \
                const int s = (kk * 4 + (lane >> 4)) ^ (row & 7);               \
                av[mi] = *(const bf16x8*)&SA[cur][row * 64 + s * 8];            \
            }                                                                   \
            _Pragma("unroll")                                                   \
            for (int nj = 0; nj < 4; ++nj) {                                    \
                const int row = wc * 64 + nj * 16 + (lane & 15);                \
                const int s = (kk * 4 + (lane >> 4)) ^ (row & 7);               \
                bw[nj] = *(const bf16x8*)&SB[cur][row * 64 + s * 8];            \
            }                                                                   \
            __builtin_amdgcn_s_setprio(1);                                      \
            _Pragma("unroll")                                                   \
            for (int mi = 0; mi < 8; ++mi)                                      \
                _Pragma("unroll")                                               \
                for (int nj = 0; nj < 4; ++nj)                                  \
                    acc[mi][nj] = __builtin_amdgcn_mfma_f32_16x16x32_bf16(      \
                        av[mi], bw[nj], acc[mi][nj], 0, 0, 0);                  \
            __builtin_amdgcn_s_setprio(0);                                      \
        }                                                                       \
    }

// GEMM1: [4096,2048]bf16 @ wqkv[3072,2048]^T + bias
//   q cols -> bf16 qb2 [b][h][s][d]  (pre-rope; rope applied in-place later)
//   k cols -> fp32 kbuf (new_k, pre-rope; rope in-place later)
//   v cols -> fp32 vbuf (new_v, final)
// N-tiles (256) never span q/k/v regions (2048|512|512).
__global__ __launch_bounds__(512, 2) void gemm_qkv_kernel(
    const uint16_t* __restrict__ xb, const uint16_t* __restrict__ wqkv,
    const float* __restrict__ bq, const float* __restrict__ bk, const float* __restrict__ bv,
    uint16_t* __restrict__ qb2, float* __restrict__ kbuf, float* __restrict__ vbuf)
{
    __shared__ __align__(16) uint16_t SA[2][256 * 64];
    __shared__ __align__(16) uint16_t SB[2][256 * 64];
    const int tid = threadIdx.x, lane = tid & 63, wid = tid >> 6;
    const int m0 = blockIdx.x * 256, n0 = blockIdx.y * 256;
    const int wr = wid >> 2, wc = wid & 3;
    const uint16_t* Ab = xb + (size_t)m0 * 2048;
    const uint16_t* Bb = wqkv + (size_t)n0 * 2048;

    GEMM256_CORE(SA, SB, Ab, Bb)

    const float* bias; int rtype; int nbase;
    if (n0 < 2048)      { bias = bq + n0;          rtype = 0; nbase = n0; }
    else if (n0 < 2560) { bias = bk + (n0 - 2048); rtype = 1; nbase = n0 - 2048; }
    else                { bias = bv + (n0 - 2560); rtype = 2; nbase = n0 - 2560; }
    #pragma unroll
    for (int mi = 0; mi < 8; ++mi) {
        #pragma unroll
        for (int nj = 0; nj < 4; ++nj) {
            const int ct = wc * 64 + nj * 16 + (lane & 15);  // tile-local col
            const int nloc = nbase + ct;
            const int head = nloc >> 7, d = nloc & 127;
            const float bval = bias[ct];
            #pragma unroll
            for (int j = 0; j < 4; ++j) {
                const int m = m0 + wr * 128 + mi * 16 + (lane >> 4) * 4 + j;
                const int bb2 = m >> 11, ss = m & 2047;
                const float v = acc[mi][nj][j] + bval;
                if (rtype == 0)
                    qb2[(((size_t)(bb2 * NQc + head) * Sc) + ss) * Dc + d] = f2bf(v);
                else if (rtype == 1)
                    kbuf[(((size_t)(bb2 * NKVc + head) * Sc) + ss) * Dc + d] = v;
                else
                    vbuf[(((size_t)(bb2 * NKVc + head) * Sc) + ss) * Dc + d] = v;
            }
        }
    }
}

// GEMM2: attn_out[4096,2048]bf16 @ Wo[2048,2048]^T -> out fp32
__global__ __launch_bounds__(512, 2) void gemm_out_kernel(
    const uint16_t* __restrict__ ab, const uint16_t* __restrict__ wob,
    float* __restrict__ C)
{
    __shared__ __align__(16) uint16_t SA[2][256 * 64];
    __shared__ __align__(16) uint16_t SB[2][256 * 64];
    const int tid = threadIdx.x, lane = tid & 63, wid = tid >> 6;
    const int m0 = blockIdx.x * 256, n0 = blockIdx.y * 256;
    const int wr = wid >> 2, wc = wid & 3;
    const uint16_t* Ab = ab + (size_t)m0 * 2048;
    const uint16_t* Bb = wob + (size_t)n0 * 2048;

    GEMM256_CORE(SA, SB, Ab, Bb)

    #pragma unroll
    for (int mi = 0; mi < 8; ++mi) {
        #pragma unroll
        for (int nj = 0; nj < 4; ++nj) {
            const int n = n0 + wc * 64 + nj * 16 + (lane & 15);
            #pragma unroll
            for (int j = 0; j < 4; ++j) {
                const int m = m0 + wr * 128 + mi * 16 + (lane >> 4) * 4 + j;
                C[(size_t)m * 2048 + n] = acc[mi][nj][j];
            }
        }
    }
}

// ---------------------------------------------------------------------------
// RoPE: q heads (0..15): bf16 in-place in qb2 (fp32 math).
//       k heads (16..19): fp32 in-place in kbuf (new_k) + bf16 copy to kb2.
// ---------------------------------------------------------------------------
__global__ __launch_bounds__(256) void rope_kernel(
    uint16_t* __restrict__ qb2, float* __restrict__ kbuf,
    const float* __restrict__ cosb, const float* __restrict__ sinb,
    uint16_t* __restrict__ kb2)
{
    const int idx = blockIdx.x * 256 + threadIdx.x;   // 2*20*2048*32 total
    const int e = idx & 31;
    int t = idx >> 5;
    const int ss = t & 2047; t >>= 11;
    const int h = t % 20, bb = t / 20;
    const float* cp = cosb + ((size_t)bb * Sc + ss) * Dc;
    const float* sp = sinb + ((size_t)bb * Sc + ss) * Dc;
    const float2 c1 = *(const float2*)(cp + 2 * e);
    const float2 c2 = *(const float2*)(cp + 64 + 2 * e);
    const float2 s1 = *(const float2*)(sp + 2 * e);
    const float2 s2 = *(const float2*)(sp + 64 + 2 * e);
    if (h < NQc) {
        const size_t base = (((size_t)(bb * NQc + h) * Sc) + ss) * Dc;
        const uint32_t u1 = *(const uint32_t*)(qb2 + base + 2 * e);
        const uint32_t u2 = *(const uint32_t*)(qb2 + base + 64 + 2 * e);
        const float x1a = bfu2f((uint16_t)u1), x1b = bfu2f((uint16_t)(u1 >> 16));
        const float x2a = bfu2f((uint16_t)u2), x2b = bfu2f((uint16_t)(u2 >> 16));
        const float lo0 = x1a * c1.x - x2a * s1.x, lo1 = x1b * c1.y - x2b * s1.y;
        const float hi0 = x2a * c2.x + x1a * s2.x, hi1 = x2b * c2.y + x1b * s2.y;
        *(uint32_t*)(qb2 + base + 2 * e)      = pk2bf(lo0, lo1);
        *(uint32_t*)(qb2 + base + 64 + 2 * e) = pk2bf(hi0, hi1);
    } else {
        const int hh = h - NQc;
        const size_t base = (((size_t)(bb * NKVc + hh) * Sc) + ss) * Dc;
        const float2 x1 = *(const float2*)(kbuf + base + 2 * e);
        const float2 x2 = *(const float2*)(kbuf + base + 64 + 2 * e);
        const float lo0 = x1.x * c1.x - x2.x * s1.x, lo1 = x1.y * c1.y - x2.y * s1.y;
        const float hi0 = x2.x * c2.x + x1.x * s2.x, hi1 = x2.y * c2.y + x1.y * s2.y;
        *(float2*)(kbuf + base + 2 * e)      = make_float2(lo0, lo1);
        *(float2*)(kbuf + base + 64 + 2 * e) = make_float2(hi0, hi1);
        *(uint32_t*)(kb2 + base + 2 * e)      = pk2bf(lo0, lo1);
        *(uint32_t*)(kb2 + base + 64 + 2 * e) = pk2bf(hi0, hi1);
    }
}

// ---------------------------------------------------------------------------
// V transpose: fp32 V[b][hk][s][d] -> bf16 Vt[b][hk][d][s]  (64s x 128d tiles)
// ---------------------------------------------------------------------------
__global__ __launch_bounds__(256) void vtrans_kernel(
    const float* __restrict__ vbuf, uint16_t* __restrict__ vt)
{
    __shared__ uint16_t T[128][72];
    const int tid = threadIdx.x;
    const int st = blockIdx.x & 31;     // s-tile
    const int bh = blockIdx.x >> 5;     // b*4+hk
    const float* src = vbuf + ((size_t)bh * Sc + st * 64) * Dc;
    #pragma unroll
    for (int i = 0; i < 8; ++i) {
        const int f = tid + 256 * i;            // 2048 float4 per 64x128 tile
        const int s_l = f >> 5, d4 = (f & 31) * 4;
        const float4 v = *((const float4*)(src + (size_t)s_l * Dc) + (f & 31));
        T[d4 + 0][s_l] = f2bf(v.x); T[d4 + 1][s_l] = f2bf(v.y);
        T[d4 + 2][s_l] = f2bf(v.z); T[d4 + 3][s_l] = f2bf(v.w);
    }
    __syncthreads();
    uint16_t* dst = vt + (size_t)bh * Dc * Sc + st * 64;
    #pragma unroll
    for (int i = 0; i < 8; ++i) {
        const int g = tid + 256 * i;            // 2048 uint2: 128 d-rows x 16 chunks
        const int d = g >> 4, s4 = (g & 15) * 4;
        *(uint2*)(dst + (size_t)d * Sc + s4) = *(const uint2*)&T[d][s4];
    }
}

// ---------------------------------------------------------------------------
// Causal GQA flash attention, bf16 MFMA (32x32x16), fp32 softmax (log2 domain).
// 1-D grid of 512 blocks; complementary (qt, 15-qt) mapping so blocks k and
// k+256 (same CU under breadth-first dispatch at 2 blocks/CU) sum to a
// constant 34 chunks -> balanced CU load.
// Block: 256 thr (4 waves), q-tile 128 rows (32/wave), K-chunks of 64.
// Swapped QK^T (mfma(K,Q) -> S^T) so each lane owns one q-row's stats.
// Q in registers; K [64][128] and Vt [128][64] double-buffered in LDS with
// XOR swizzle via pre-swizzled global_load_lds sources.
// P -> A-frags via v_cvt_pk_bf16_f32 + v_permlane32_swap_b32 (T12).
// Defer-rescale threshold 8 (log2 domain) skips O-rescale most chunks (T13).
// ---------------------------------------------------------------------------
__global__ __launch_bounds__(256, 2) void attn_kernel(
    const uint16_t* __restrict__ qb, const uint16_t* __restrict__ kb,
    const uint16_t* __restrict__ vt, uint16_t* __restrict__ ab)
{
    __shared__ __align__(16) uint16_t Ks[2][64 * 128];
    __shared__ __align__(16) uint16_t Vs[2][128 * 64];

    const int tid = threadIdx.x, lane = tid & 63, wid = tid >> 6;
    const int lin = blockIdx.x;
    const int hf = lin >> 8, pp = lin & 255;
    const int qt = hf ? (pp & 15) : (15 - (pp & 15));   // complementary pairing
    const int bh = (pp >> 4) + hf * 16;
    const int b = bh >> 4, h = bh & 15, hk = h >> 2;
    const int l31 = lane & 31, l5 = lane >> 5;

    const uint16_t* kpB = kb + ((size_t)(b * NKVc + hk) * Sc) * Dc;
    const uint16_t* vpB = vt + ((size_t)(b * NKVc + hk) * Dc) * Sc;

    // Q fragments in registers: B-operand, lane = q-col (l31), k = d
    const uint16_t* qbase =
        qb + (((size_t)(b * NQc + h) * Sc) + qt * 128 + wid * 32 + l31) * Dc;
    bf16x8 qf[8];
    #pragma unroll
    for (int kk = 0; kk < 8; ++kk)
        qf[kk] = *(const bf16x8*)(qbase + kk * 16 + l5 * 8);

    float m_r = -INFINITY, l_r = 0.f;
    f32x16 o0 = {}, o1 = {}, o2 = {}, o3 = {};

    const int qg      = qt * 128 + wid * 32 + l31;  // this lane's q row
    const int qgw_min = qt * 128 + wid * 32;        // wave's min q row
    const int qgw_max = qgw_min + 31;               // wave's max q row
    const int NCH = 2 * qt + 2;
    constexpr float SCL2 = 0.08838834764831845f * 1.4426950408889634f; // SCALE*log2e

    auto stage = [&](int ch, int buf) {
        const int kb0 = ch * 64;
        #pragma unroll
        for (int i = 0; i < 4; ++i) {          // K: 16 insts total, 4/wave
            const int g = wid * 4 + i;
            const int row = g * 4 + (lane >> 4);
            const int slot = (lane & 15) ^ (row & 15);
            lds_load16(&Ks[buf][g * 512], kpB + (size_t)(kb0 + row) * Dc + slot * 8);
        }
        #pragma unroll
        for (int i = 0; i < 4; ++i) {          // Vt: 16 insts total, 4/wave
            const int g = wid * 4 + i;
            const int d = g * 8 + (lane >> 3);
            const int slot = (lane & 7) ^ (d & 7);
            lds_load16(&Vs[buf][g * 512], vpB + (size_t)d * Sc + kb0 + slot * 8);
        }
    };

    stage(0, 0);
    __syncthreads();

    for (int ch = 0; ch < NCH; ++ch) {
        const int buf = ch & 1;
        if (ch + 1 < NCH) stage(ch + 1, buf ^ 1);
        const int kb0 = ch * 64;

        if (kb0 <= qgw_max) {   // wave-uniform: skip fully-masked chunks
            // ---- QK^T (S^T): A = K rows, B = Q
            f32x16 s0 = {}, s1 = {};
            __builtin_amdgcn_s_setprio(1);
            #pragma unroll
            for (int kk = 0; kk < 8; ++kk) {
                const int r0 = l31;
                const int sl0 = (kk * 2 + l5) ^ (r0 & 15);
                const bf16x8 a0 = *(const bf16x8*)&Ks[buf][r0 * 128 + sl0 * 8];
                const int r1 = 32 + l31;
                const int sl1 = (kk * 2 + l5) ^ (r1 & 15);
                const bf16x8 a1 = *(const bf16x8*)&Ks[buf][r1 * 128 + sl1 * 8];
                s0 = __builtin_amdgcn_mfma_f32_32x32x16_bf16(a0, qf[kk], s0, 0, 0, 0);
                s1 = __builtin_amdgcn_mfma_f32_32x32x16_bf16(a1, qf[kk], s1, 0, 0, 0);
            }
            __builtin_amdgcn_s_setprio(0);

            // ---- logits in log2 domain; mask only when the chunk can cross
            float p[32];
            const bool needmask = (kb0 + 63 > qgw_min);
            #pragma unroll
            for (int r = 0; r < 16; ++r) {
                float v0 = s0[r] * SCL2;
                float v1 = s1[r] * SCL2;
                if (needmask) {
                    const int krel = (r & 3) + 8 * (r >> 2) + 4 * l5;
                    if (kb0 + krel > qg)      v0 = -INFINITY;
                    if (kb0 + 32 + krel > qg) v1 = -INFINITY;
                }
                p[r] = v0; p[16 + r] = v1;
            }
            // ---- tree max (depth 5) + cross-half
            float tm[16];
            #pragma unroll
            for (int i = 0; i < 16; ++i) tm[i] = fmaxf(p[i], p[16 + i]);
            #pragma unroll
            for (int i = 0; i < 8; ++i) tm[i] = fmaxf(tm[i], tm[8 + i]);
            #pragma unroll
            for (int i = 0; i < 4; ++i) tm[i] = fmaxf(tm[i], tm[4 + i]);
            float rm = fmaxf(fmaxf(tm[0], tm[1]), fmaxf(tm[2], tm[3]));
            rm = fmaxf(rm, __shfl_xor(rm, 32));

            // ---- defer-rescale (T13): skip O-rescale unless max grew > 8
            if (!__all(rm <= m_r + 8.0f)) {
                const float mnew = fmaxf(m_r, rm);
                const float alpha = exp2f(m_r - mnew);
                #pragma unroll
                for (int r = 0; r < 16; ++r) {
                    const int qi = (r & 3) + 8 * (r >> 2) + 4 * l5;
                    const float av = __shfl(alpha, qi);
                    o0[r] *= av; o1[r] *= av; o2[r] *= av; o3[r] *= av;
                }
                l_r *= alpha;
                m_r = mnew;
            }

            // ---- exponentials (bounded by 2^8 under defer) + tree sum
            #pragma unroll
            for (int j = 0; j < 32; ++j) p[j] = exp2f(p[j] - m_r);
            float s8[8];
            #pragma unroll
            for (int i = 0; i < 8; ++i)
                s8[i] = (p[i] + p[8 + i]) + (p[16 + i] + p[24 + i]);
            float sum = ((s8[0] + s8[1]) + (s8[2] + s8[3]))
                      + ((s8[4] + s8[5]) + (s8[6] + s8[7]));
            sum += __shfl_xor(sum, 32);
            l_r += sum;

            // ---- pack P to bf16 pairs (RNE) with v_cvt_pk
            uint32_t pb[16];
            #pragma unroll
            for (int j = 0; j < 8; ++j) {
                asm("v_cvt_pk_bf16_f32 %0, %1, %2"
                    : "=v"(pb[j]) : "v"(p[2 * j]), "v"(p[2 * j + 1]));
                asm("v_cvt_pk_bf16_f32 %0, %1, %2"
                    : "=v"(pb[8 + j]) : "v"(p[16 + 2 * j]), "v"(p[16 + 2 * j + 1]));
            }
            // ---- build PV A-frags: swap(pb[4g],pb[4g+2]) -> words 0,2;
            //      swap(pb[4g+1],pb[4g+3]) -> words 1,3  (verified lane algebra)
            #pragma unroll
            for (int g2 = 0; g2 < 4; ++g2) {
                asm("v_permlane32_swap_b32 %0, %1"
                    : "+v"(pb[4 * g2 + 0]), "+v"(pb[4 * g2 + 2]));
                asm("v_permlane32_swap_b32 %0, %1"
                    : "+v"(pb[4 * g2 + 1]), "+v"(pb[4 * g2 + 3]));
            }
            const bf16x8 pa0 = mk8(pb[0],  pb[1],  pb[2],  pb[3]);
            const bf16x8 pa1 = mk8(pb[4],  pb[5],  pb[6],  pb[7]);
            const bf16x8 pa2 = mk8(pb[8],  pb[9],  pb[10], pb[11]);
            const bf16x8 pa3 = mk8(pb[12], pb[13], pb[14], pb[15]);

            // ---- PV: B = Vt rows (d), k = keys
            __builtin_amdgcn_s_setprio(1);
            #define PV_DV(OO, DV)                                                        \
            {                                                                            \
                const int d = (DV) * 32 + l31;                                           \
                const int rb = d * 64; const int sw = d & 7;                             \
                const bf16x8 b0 = *(const bf16x8*)&Vs[buf][rb + ((0 * 2 + l5) ^ sw) * 8];\
                OO = __builtin_amdgcn_mfma_f32_32x32x16_bf16(pa0, b0, OO, 0, 0, 0);      \
                const bf16x8 b1 = *(const bf16x8*)&Vs[buf][rb + ((1 * 2 + l5) ^ sw) * 8];\
                OO = __builtin_amdgcn_mfma_f32_32x32x16_bf16(pa1, b1, OO, 0, 0, 0);      \
                const bf16x8 b2 = *(const bf16x8*)&Vs[buf][rb + ((2 * 2 + l5) ^ sw) * 8];\
                OO = __builtin_amdgcn_mfma_f32_32x32x16_bf16(pa2, b2, OO, 0, 0, 0);      \
                const bf16x8 b3 = *(const bf16x8*)&Vs[buf][rb + ((3 * 2 + l5) ^ sw) * 8];\
                OO = __builtin_amdgcn_mfma_f32_32x32x16_bf16(pa3, b3, OO, 0, 0, 0);      \
            }
            PV_DV(o0, 0) PV_DV(o1, 1) PV_DV(o2, 2) PV_DV(o3, 3)
            #undef PV_DV
            __builtin_amdgcn_s_setprio(0);
        }

        __syncthreads();
    }

    // ---- epilogue: normalize, write bf16 attn_out [b][s][h*128+d]
    const float inv = 1.f / (l_r + 1e-9f);
    uint16_t* abase = ab + ((size_t)b * Sc) * 2048 + (size_t)h * Dc;
    #pragma unroll
    for (int r = 0; r < 16; ++r) {
        const int qi = (r & 3) + 8 * (r >> 2) + 4 * l5;
        const float iv = __shfl(inv, qi);
        const int srow = qt * 128 + wid * 32 + qi;
        uint16_t* dst = abase + (size_t)srow * 2048 + l31;
        dst[0]  = f2bf(o0[r] * iv);
        dst[32] = f2bf(o1[r] * iv);
        dst[64] = f2bf(o2[r] * iv);
        dst[96] = f2bf(o3[r] * iv);
    }
}

// ---------------------------------------------------------------------------
// Workspace plan (fits the known-safe 32 MiB):
//   [0,16Mi):  xb -> dead after gemm_qkv -> ab
//   [16,28Mi): wqkv -> dead after gemm_qkv -> kb2 [16,20Mi) + vb2t [20,24Mi)
//   [24,32Mi): wob (written by cvt2 after gemm_qkv)
// d_out: [0,16Mi) parks bf16 Q until gemm_out overwrites with fp32 out.
// ---------------------------------------------------------------------------
extern "C" void kernel_launch(void* const* d_in, const int* in_sizes, int n_in,
                              void* d_out, int out_size, void* d_ws, size_t ws_size,
                              hipStream_t stream)
{
    const float* x    = (const float*)d_in[0];
    const float* cosb = (const float*)d_in[1];
    const float* sinb = (const float*)d_in[2];
    const float* Wq   = (const float*)d_in[3];
    const float* bq   = (const float*)d_in[4];
    const float* Wk   = (const float*)d_in[5];
    const float* bk   = (const float*)d_in[6];
    const float* Wv   = (const float*)d_in[7];
    const float* bv   = (const float*)d_in[8];
    const float* Wo   = (const float*)d_in[9];

    float* out  = (float*)d_out;                          // [B,S,H] fp32
    float* kout = out  + (size_t)Bc * Sc * Hc;            // new_k fp32
    float* vout = kout + (size_t)Bc * NKVc * Sc * Dc;     // new_v fp32
    uint16_t* qb2 = (uint16_t*)out;                       // bf16 Q parked in out region

    uint8_t* ws = (uint8_t*)d_ws;
    uint16_t* xb   = (uint16_t*)(ws);                     // [0,16Mi)
    uint16_t* wqkv = (uint16_t*)(ws + (16u << 20));       // [16,28Mi)
    uint16_t* kb2  = (uint16_t*)(ws + (16u << 20));       // [16,20Mi) after wqkv dies
    uint16_t* vb2t = (uint16_t*)(ws + (20u << 20));       // [20,24Mi)
    uint16_t* wob  = (uint16_t*)(ws + (24u << 20));       // [24,32Mi)
    uint16_t* ab   = (uint16_t*)(ws);                     // [0,16Mi) after xb dies

    cvt1_kernel<<<2048, 256, 0, stream>>>(x, Wq, Wk, Wv, xb, wqkv);

    gemm_qkv_kernel<<<dim3(16, 12), 512, 0, stream>>>(xb, wqkv, bq, bk, bv,
                                                      qb2, kout, vout);

    rope_kernel<<<10240, 256, 0, stream>>>(qb2, kout, cosb, sinb, kb2);

    vtrans_kernel<<<256, 256, 0, stream>>>(vout, vb2t);

    cvt2_kernel<<<1024, 256, 0, stream>>>(Wo, wob);

    attn_kernel<<<512, 256, 0, stream>>>(qb2, kb2, vb2t, ab);

    gemm_out_kernel<<<dim3(16, 8), 512, 0, stream>>>(ab, wob, out);
}